// Round 2
// baseline (735.048 us; speedup 1.0000x reference)
//
#include <hip/hip_runtime.h>
#include <cmath>

#define H 8
#define D 128
#define HD 1024            // H*D
#define NMAX 1024
#define BS 32
#define NB 32
#define S_SEL 8
#define SCALE 0.08838834764831845f   // 1/sqrt(128)
#define SENT -3.0e38f

__device__ __forceinline__ float wave_sum(float v) {
#pragma unroll
    for (int off = 32; off > 0; off >>= 1) v += __shfl_xor(v, off);
    return v;
}

// ---------------------------------------------------------------------------
// K1: write padded qp, kp into d_out (outputs 1 and 2)
// ---------------------------------------------------------------------------
__global__ __launch_bounds__(256) void pad_qk_kernel(
    const float* __restrict__ q, const float* __restrict__ k,
    const int* __restrict__ offs,
    float* __restrict__ qp, float* __restrict__ kp) {
    int idx = blockIdx.x * 256 + threadIdx.x;       // float4 index over [B,n,H,D/4]
    int d4 = idx & 31;
    int h  = (idx >> 5) & 7;
    int m  = (idx >> 8) & (NMAX - 1);
    int b  = idx >> 18;                              // / (1024*8*32)
    int o0 = offs[b];
    int len = offs[b + 1] - o0;
    float4 qv = make_float4(0.f, 0.f, 0.f, 0.f);
    float4 kv = qv;
    if (m < len) {
        size_t src = (size_t)(o0 + m) * HD + h * D + d4 * 4;
        qv = *(const float4*)(q + src);
        kv = *(const float4*)(k + src);
    }
    *(float4*)(qp + (size_t)idx * 4) = qv;
    *(float4*)(kp + (size_t)idx * 4) = kv;
}

// ---------------------------------------------------------------------------
// K2: block compression: k_cmp/v_cmp[b,kb,h,d] = mean over 32 positions
// (padded positions contribute zero; divide by 32 always, as reference does)
// ---------------------------------------------------------------------------
__global__ __launch_bounds__(256) void compress_kernel(
    const float* __restrict__ k, const float* __restrict__ v,
    const int* __restrict__ offs,
    float* __restrict__ k_cmp, float* __restrict__ v_cmp) {
    int idx = blockIdx.x * 256 + threadIdx.x;       // float4 index over [B,NB,H,D/4]
    int d4 = idx & 31;
    int h  = (idx >> 5) & 7;
    int kb = (idx >> 8) & (NB - 1);
    int b  = idx >> 13;                              // / (32*8*32)
    int o0 = offs[b];
    int len = offs[b + 1] - o0;
    float4 ks = make_float4(0.f, 0.f, 0.f, 0.f);
    float4 vs = ks;
    int base = kb * BS;
#pragma unroll 4
    for (int j = 0; j < BS; j++) {
        int pos = base + j;
        if (pos < len) {
            size_t src = (size_t)(o0 + pos) * HD + h * D + d4 * 4;
            float4 kk = *(const float4*)(k + src);
            float4 vv = *(const float4*)(v + src);
            ks.x += kk.x; ks.y += kk.y; ks.z += kk.z; ks.w += kk.w;
            vs.x += vv.x; vs.y += vv.y; vs.z += vv.z; vs.w += vv.w;
        }
    }
    const float inv = 1.f / 32.f;
    ks.x *= inv; ks.y *= inv; ks.z *= inv; ks.w *= inv;
    vs.x *= inv; vs.y *= inv; vs.z *= inv; vs.w *= inv;
    *(float4*)(k_cmp + (size_t)idx * 4) = ks;
    *(float4*)(v_cmp + (size_t)idx * 4) = vs;
}

// ---------------------------------------------------------------------------
// K3: gates g[b,m,h,{0,1}] = sigmoid(q . Wg[h,:,e] + bg[h,e]) for valid rows
// one wave per (b,m,h) row
// ---------------------------------------------------------------------------
__global__ __launch_bounds__(256) void gates_kernel(
    const float* __restrict__ q, const float* __restrict__ Wg,
    const float* __restrict__ bg, const int* __restrict__ offs,
    float* __restrict__ g) {
    int row  = blockIdx.x * 4 + (threadIdx.x >> 6);   // (b*N + m)*H + h
    int lane = threadIdx.x & 63;
    int h = row & 7;
    int m = (row >> 3) & (NMAX - 1);
    int b = row >> 13;
    int o0 = offs[b];
    int len = offs[b + 1] - o0;
    if (m >= len) return;
    size_t qb = (size_t)(o0 + m) * HD + h * D + lane * 2;
    float2 q2 = *(const float2*)(q + qb);
    int wb = (h * D + lane * 2) * 3;                  // Wg[h,d,e] at (h*D+d)*3+e
    float p0 = q2.x * Wg[wb + 0] + q2.y * Wg[wb + 3];
    float p1 = q2.x * Wg[wb + 1] + q2.y * Wg[wb + 4];
    p0 = wave_sum(p0);
    p1 = wave_sum(p1);
    if (lane == 0) {
        float g0 = 1.f / (1.f + expf(-(p0 + bg[h * 3 + 0])));
        float g1 = 1.f / (1.f + expf(-(p1 + bg[h * 3 + 1])));
        float* gp = g + (size_t)row * 2;
        gp[0] = g0; gp[1] = g1;
    }
}

// ---------------------------------------------------------------------------
// K4: compressed attention + top-8 causal block selection
// one wave per (b,h,m) row
// ---------------------------------------------------------------------------
__global__ __launch_bounds__(256) void cmp_attn_kernel(
    const float* __restrict__ q, const float* __restrict__ k_cmp,
    const float* __restrict__ v_cmp, const float* __restrict__ g,
    const int* __restrict__ offs,
    float* __restrict__ o_cmp_j, int* __restrict__ topk) {
    int row  = blockIdx.x * 4 + (threadIdx.x >> 6);   // (b*H + h)*N + m
    int lane = threadIdx.x & 63;
    int m = row & (NMAX - 1);
    int h = (row >> 10) & 7;
    int b = row >> 13;
    int o0 = offs[b];
    int len = offs[b + 1] - o0;
    if (m >= len) return;
    int tok = o0 + m;
    float2 q2 = *(const float2*)(q + (size_t)tok * HD + h * D + lane * 2);
    int qblk = m >> 5;
    float myscore = SENT;                              // lane kb keeps score[kb]
    float2 acc = make_float2(0.f, 0.f);
    for (int kb = 0; kb <= qblk; kb++) {
        size_t cb = ((size_t)(b * NB + kb) * H + h) * D + lane * 2;
        float2 k2 = *(const float2*)(k_cmp + cb);
        float sc = wave_sum(q2.x * k2.x + q2.y * k2.y) * SCALE;
        if (lane == kb) myscore = sc;
        float p = sc / (1.f + expf(-sc));              // silu
        float2 v2 = *(const float2*)(v_cmp + cb);
        acc.x += p * v2.x;
        acc.y += p * v2.y;
    }
    float gc = g[(size_t)((b * NMAX + m) * H + h) * 2];
    acc.x *= gc; acc.y *= gc;
    *(float2*)(o_cmp_j + (size_t)tok * HD + h * D + lane * 2) = acc;

    // top-8 (desc value, tie -> lower index), -1 padding
    bool taken = false;
    int* tk = topk + (size_t)row * S_SEL;
    for (int it = 0; it < S_SEL; it++) {
        float v = taken ? SENT : myscore;
        int idx = lane;
#pragma unroll
        for (int off = 32; off > 0; off >>= 1) {
            float ov = __shfl_xor(v, off);
            int oi = __shfl_xor(idx, off);
            if (ov > v || (ov == v && oi < idx)) { v = ov; idx = oi; }
        }
        int sel = (v > -2.9e38f) ? idx : -1;
        if (lane == 0) tk[it] = sel;
        if (sel == lane) taken = true;
    }
}

// ---------------------------------------------------------------------------
// K5: selected (gathered top-k block) attention
// one workgroup (4 waves) per (b,h,m); each wave does 2 selected blocks:
//   QK: lanes 0-31 -> block 2w key j, lanes 32-63 -> block 2w+1 key j
//   PV: each lane owns dims {2l, 2l+1}, broadcast p via shfl
// ---------------------------------------------------------------------------
__global__ __launch_bounds__(256) void sel_attn_kernel(
    const float* __restrict__ q, const float* __restrict__ k,
    const float* __restrict__ v, const float* __restrict__ g,
    const int* __restrict__ offs, const int* __restrict__ topk,
    float* __restrict__ o_slc_j) {
    int row = blockIdx.x;                              // (b*H + h)*N + m
    int m = row & (NMAX - 1);
    int h = (row >> 10) & 7;
    int b = row >> 13;
    int o0 = offs[b];
    int len = offs[b + 1] - o0;
    if (m >= len) return;                              // uniform across block
    int tok = o0 + m;
    __shared__ float qs[D];
    __shared__ float accs[4][D];
    int tid = threadIdx.x;
    if (tid < D) qs[tid] = q[(size_t)tok * HD + h * D + tid];
    __syncthreads();
    int w = tid >> 6, lane = tid & 63;
    const int* tk = topk + (size_t)row * S_SEL;
    int blk0 = tk[2 * w], blk1 = tk[2 * w + 1];
    int myblk = (lane < 32) ? blk0 : blk1;
    int j = lane & 31;
    float p = 0.f;
    if (myblk >= 0) {
        int kpos = myblk * BS + j;
        if (kpos <= m) {
            const float4* kp4 = (const float4*)(k + (size_t)(o0 + kpos) * HD + h * D);
            const float4* q4 = (const float4*)qs;
            float sc = 0.f;
#pragma unroll
            for (int d4 = 0; d4 < 32; d4++) {
                float4 kk = kp4[d4];
                float4 qq = q4[d4];
                sc += qq.x * kk.x + qq.y * kk.y + qq.z * kk.z + qq.w * kk.w;
            }
            sc *= SCALE;
            p = sc / (1.f + expf(-sc));
        }
    }
    float2 acc = make_float2(0.f, 0.f);
    for (int jj = 0; jj < 64; jj++) {
        float pj = __shfl(p, jj);
        int sb = (jj < 32) ? blk0 : blk1;
        if (sb < 0) continue;                          // wave-uniform branch
        size_t vt = ((size_t)(o0 + sb * BS + (jj & 31))) * HD + h * D + lane * 2;
        float2 v2 = *(const float2*)(v + vt);
        acc.x += pj * v2.x;
        acc.y += pj * v2.y;
    }
    accs[w][lane * 2] = acc.x;
    accs[w][lane * 2 + 1] = acc.y;
    __syncthreads();
    if (tid < D) {
        float s = accs[0][tid] + accs[1][tid] + accs[2][tid] + accs[3][tid];
        float gs = g[(size_t)((b * NMAX + m) * H + h) * 2 + 1];
        o_slc_j[(size_t)tok * HD + h * D + tid] = s * gs;
    }
}

// ---------------------------------------------------------------------------
// K6: LayerNorm(1024) per stream, gate by u, sum -> out
// one workgroup per token. NOTE: oc may alias out (each thread reads its own
// float4 before writing the same address; no cross-thread hazard).
// ---------------------------------------------------------------------------
__global__ __launch_bounds__(256) void ln_combine_kernel(
    const float* __restrict__ oc, const float* __restrict__ os,
    const float* __restrict__ u, float* __restrict__ out) {
    int t = blockIdx.x, tid = threadIdx.x;
    size_t base = (size_t)t * HD;
    float4 xc = *(const float4*)(oc + base + tid * 4);
    float4 xs = *(const float4*)(os + base + tid * 4);
    float4 uu = *(const float4*)(u + base + tid * 4);
    float s_c = xc.x + xc.y + xc.z + xc.w;
    float q_c = xc.x * xc.x + xc.y * xc.y + xc.z * xc.z + xc.w * xc.w;
    float s_s = xs.x + xs.y + xs.z + xs.w;
    float q_s = xs.x * xs.x + xs.y * xs.y + xs.z * xs.z + xs.w * xs.w;
    s_c = wave_sum(s_c); q_c = wave_sum(q_c);
    s_s = wave_sum(s_s); q_s = wave_sum(q_s);
    __shared__ float red[4][4];
    int w = tid >> 6, lane = tid & 63;
    if (lane == 0) {
        red[w][0] = s_c; red[w][1] = q_c; red[w][2] = s_s; red[w][3] = q_s;
    }
    __syncthreads();
    float tsc = red[0][0] + red[1][0] + red[2][0] + red[3][0];
    float tqc = red[0][1] + red[1][1] + red[2][1] + red[3][1];
    float tss = red[0][2] + red[1][2] + red[2][2] + red[3][2];
    float tqs = red[0][3] + red[1][3] + red[2][3] + red[3][3];
    const float inv = 1.f / 1024.f;
    float mc = tsc * inv, vc = tqc * inv - mc * mc;
    float ms = tss * inv, vs = tqs * inv - ms * ms;
    float rc = rsqrtf(vc + 1e-5f), rs = rsqrtf(vs + 1e-5f);
    float4 o;
    o.x = ((xc.x - mc) * rc + (xs.x - ms) * rs) * uu.x;
    o.y = ((xc.y - mc) * rc + (xs.y - ms) * rs) * uu.y;
    o.z = ((xc.z - mc) * rc + (xs.z - ms) * rs) * uu.z;
    o.w = ((xc.w - mc) * rc + (xs.w - ms) * rs) * uu.w;
    *(float4*)(out + base + tid * 4) = o;
}

// ---------------------------------------------------------------------------
extern "C" void kernel_launch(void* const* d_in, const int* in_sizes, int n_in,
                              void* d_out, int out_size, void* d_ws, size_t ws_size,
                              hipStream_t stream) {
    const float* q  = (const float*)d_in[0];
    const float* k  = (const float*)d_in[1];
    const float* v  = (const float*)d_in[2];
    const float* u  = (const float*)d_in[3];
    const float* Wg = (const float*)d_in[4];
    const float* bg = (const float*)d_in[5];
    const int* offs = (const int*)d_in[6];   // int32! (jnp default, x64 disabled)

    int B = in_sizes[6] - 1;
    int T = in_sizes[0] / HD;

    float* out = (float*)d_out;
    float* qp  = out + (size_t)T * HD;
    float* kp  = qp + (size_t)B * NMAX * HD;

    // o_cmp_j aliases the final out region (see ln_combine_kernel note)
    float* o_cmp_j = out;

    char* w = (char*)d_ws;
    float* k_cmp = (float*)w;            w += (size_t)B * NB * HD * 4;
    float* v_cmp = (float*)w;            w += (size_t)B * NB * HD * 4;
    float* g     = (float*)w;            w += (size_t)B * NMAX * H * 2 * 4;
    int*   topk  = (int*)w;              w += (size_t)B * H * NMAX * S_SEL * 4;
    float* o_slc_j = (float*)w;

    int padBlocks  = (B * NMAX * HD / 4) / 256;       // B*1024
    int cmpBlocks  = (B * NB * HD / 4) / 256;         // B*32
    int gateBlocks = (B * NMAX * H) / 4;              // B*2048
    int attBlocks  = (B * H * NMAX) / 4;              // B*2048
    int selBlocks  = B * H * NMAX;                    // B*8192

    pad_qk_kernel<<<padBlocks, 256, 0, stream>>>(q, k, offs, qp, kp);
    compress_kernel<<<cmpBlocks, 256, 0, stream>>>(k, v, offs, k_cmp, v_cmp);
    gates_kernel<<<gateBlocks, 256, 0, stream>>>(q, Wg, bg, offs, g);
    cmp_attn_kernel<<<attBlocks, 256, 0, stream>>>(q, k_cmp, v_cmp, g, offs, o_cmp_j, topk);
    sel_attn_kernel<<<selBlocks, 256, 0, stream>>>(q, k, v, g, offs, topk, o_slc_j);
    ln_combine_kernel<<<T, 256, 0, stream>>>(o_cmp_j, o_slc_j, u, out);
}

// Round 3
// 439.332 us; speedup vs baseline: 1.6731x; 1.6731x over previous
//
#include <hip/hip_runtime.h>
#include <cmath>

#define H 8
#define D 128
#define HD 1024            // H*D
#define NMAX 1024
#define BS 32
#define NB 32
#define S_SEL 8
#define SCALE 0.08838834764831845f   // 1/sqrt(128)
#define SENT -3.0e38f
#define LDST 132           // LDS row stride: 128 + 4 pad (16B-aligned rows)

__device__ __forceinline__ float wave_sum(float v) {
#pragma unroll
    for (int off = 32; off > 0; off >>= 1) v += __shfl_xor(v, off);
    return v;
}

__device__ __forceinline__ float silu(float x) {
    return x / (1.f + expf(-x));
}

// ---------------------------------------------------------------------------
// K1: write padded qp, kp into d_out (outputs 1 and 2)
// ---------------------------------------------------------------------------
__global__ __launch_bounds__(256) void pad_qk_kernel(
    const float* __restrict__ q, const float* __restrict__ k,
    const int* __restrict__ offs,
    float* __restrict__ qp, float* __restrict__ kp) {
    int idx = blockIdx.x * 256 + threadIdx.x;       // float4 index over [B,n,H,D/4]
    int d4 = idx & 31;
    int h  = (idx >> 5) & 7;
    int m  = (idx >> 8) & (NMAX - 1);
    int b  = idx >> 18;
    int o0 = offs[b];
    int len = offs[b + 1] - o0;
    float4 qv = make_float4(0.f, 0.f, 0.f, 0.f);
    float4 kv = qv;
    if (m < len) {
        size_t src = (size_t)(o0 + m) * HD + h * D + d4 * 4;
        qv = *(const float4*)(q + src);
        kv = *(const float4*)(k + src);
    }
    *(float4*)(qp + (size_t)idx * 4) = qv;
    *(float4*)(kp + (size_t)idx * 4) = kv;
}

// ---------------------------------------------------------------------------
// K2: block compression means
// ---------------------------------------------------------------------------
__global__ __launch_bounds__(256) void compress_kernel(
    const float* __restrict__ k, const float* __restrict__ v,
    const int* __restrict__ offs,
    float* __restrict__ k_cmp, float* __restrict__ v_cmp) {
    int idx = blockIdx.x * 256 + threadIdx.x;       // float4 index over [B,NB,H,D/4]
    int d4 = idx & 31;
    int h  = (idx >> 5) & 7;
    int kb = (idx >> 8) & (NB - 1);
    int b  = idx >> 13;
    int o0 = offs[b];
    int len = offs[b + 1] - o0;
    float4 ks = make_float4(0.f, 0.f, 0.f, 0.f);
    float4 vs = ks;
    int base = kb * BS;
#pragma unroll 4
    for (int j = 0; j < BS; j++) {
        int pos = base + j;
        if (pos < len) {
            size_t src = (size_t)(o0 + pos) * HD + h * D + d4 * 4;
            float4 kk = *(const float4*)(k + src);
            float4 vv = *(const float4*)(v + src);
            ks.x += kk.x; ks.y += kk.y; ks.z += kk.z; ks.w += kk.w;
            vs.x += vv.x; vs.y += vv.y; vs.z += vv.z; vs.w += vv.w;
        }
    }
    const float inv = 1.f / 32.f;
    ks.x *= inv; ks.y *= inv; ks.z *= inv; ks.w *= inv;
    vs.x *= inv; vs.y *= inv; vs.z *= inv; vs.w *= inv;
    *(float4*)(k_cmp + (size_t)idx * 4) = ks;
    *(float4*)(v_cmp + (size_t)idx * 4) = vs;
}

// ---------------------------------------------------------------------------
// K3: gates
// ---------------------------------------------------------------------------
__global__ __launch_bounds__(256) void gates_kernel(
    const float* __restrict__ q, const float* __restrict__ Wg,
    const float* __restrict__ bg, const int* __restrict__ offs,
    float* __restrict__ g) {
    int row  = blockIdx.x * 4 + (threadIdx.x >> 6);   // (b*N + m)*H + h
    int lane = threadIdx.x & 63;
    int h = row & 7;
    int m = (row >> 3) & (NMAX - 1);
    int b = row >> 13;
    int o0 = offs[b];
    int len = offs[b + 1] - o0;
    if (m >= len) return;
    size_t qb = (size_t)(o0 + m) * HD + h * D + lane * 2;
    float2 q2 = *(const float2*)(q + qb);
    int wb = (h * D + lane * 2) * 3;
    float p0 = q2.x * Wg[wb + 0] + q2.y * Wg[wb + 3];
    float p1 = q2.x * Wg[wb + 1] + q2.y * Wg[wb + 4];
    p0 = wave_sum(p0);
    p1 = wave_sum(p1);
    if (lane == 0) {
        float g0 = 1.f / (1.f + expf(-(p0 + bg[h * 3 + 0])));
        float g1 = 1.f / (1.f + expf(-(p1 + bg[h * 3 + 1])));
        float* gp = g + (size_t)row * 2;
        gp[0] = g0; gp[1] = g1;
    }
}

// ---------------------------------------------------------------------------
// K4: compressed attention + top-8 block selection -> bitmask
// one wave per (b,h,m) row
// ---------------------------------------------------------------------------
__global__ __launch_bounds__(256) void cmp_attn_kernel(
    const float* __restrict__ q, const float* __restrict__ k_cmp,
    const float* __restrict__ v_cmp, const float* __restrict__ g,
    const int* __restrict__ offs,
    float* __restrict__ o_cmp_j, unsigned* __restrict__ selmask) {
    int row  = blockIdx.x * 4 + (threadIdx.x >> 6);   // (b*H + h)*N + m
    int lane = threadIdx.x & 63;
    int m = row & (NMAX - 1);
    int h = (row >> 10) & 7;
    int b = row >> 13;
    int o0 = offs[b];
    int len = offs[b + 1] - o0;
    if (m >= len) return;
    int tok = o0 + m;
    float2 q2 = *(const float2*)(q + (size_t)tok * HD + h * D + lane * 2);
    int qblk = m >> 5;
    float myscore = SENT;                              // lane kb keeps score[kb]
    float2 acc = make_float2(0.f, 0.f);
    for (int kb = 0; kb <= qblk; kb++) {
        size_t cb = ((size_t)(b * NB + kb) * H + h) * D + lane * 2;
        float2 k2 = *(const float2*)(k_cmp + cb);
        float sc = wave_sum(q2.x * k2.x + q2.y * k2.y) * SCALE;
        if (lane == kb) myscore = sc;
        float p = silu(sc);
        float2 v2 = *(const float2*)(v_cmp + cb);
        acc.x += p * v2.x;
        acc.y += p * v2.y;
    }
    float gc = g[(size_t)((b * NMAX + m) * H + h) * 2];
    acc.x *= gc; acc.y *= gc;
    *(float2*)(o_cmp_j + (size_t)tok * HD + h * D + lane * 2) = acc;

    // top-8 (desc value, tie -> lower index) -> bitmask; butterfly leaves
    // identical (v,idx) in all lanes, so every lane tracks the same mask.
    bool taken = false;
    unsigned mask = 0;
    for (int it = 0; it < S_SEL; it++) {
        float v = taken ? SENT : myscore;
        int idx = lane;
#pragma unroll
        for (int off = 32; off > 0; off >>= 1) {
            float ov = __shfl_xor(v, off);
            int oi = __shfl_xor(idx, off);
            if (ov > v || (ov == v && oi < idx)) { v = ov; idx = oi; }
        }
        if (v > -2.9e38f) {
            mask |= (1u << idx);
            if (idx == lane) taken = true;
        }
    }
    if (lane == 0) selmask[row] = mask;
}

// ---------------------------------------------------------------------------
// K5: selected attention, qblk-centric.
// One workgroup per (b,h,qblk): 32-query tile. Stage Q once; loop key-blocks
// in the UNION of the 32 queries' selection masks; stage K/V block to LDS
// (coalesced); 4 waves each own an 8-query slice:
//   QK: 2x2 micro-tile per lane (m1=m0+4, j1=j0+16 keeps LDS banks 2-way max)
//   PV: per-lane 2 m-rows x 8 d accumulators via wave-private P tile.
// ---------------------------------------------------------------------------
__global__ __launch_bounds__(256) void sel_attn_v2(
    const float* __restrict__ q, const float* __restrict__ k,
    const float* __restrict__ v, const float* __restrict__ g,
    const int* __restrict__ offs, const unsigned* __restrict__ selmask,
    float* __restrict__ o_slc_j) {
    int x = blockIdx.x;                 // ((b*H + h)*NB + qblk)
    int qblk = x & (NB - 1);
    int h = (x >> 5) & 7;
    int b = x >> 8;
    int o0 = offs[b];
    int len = offs[b + 1] - o0;
    if (qblk * BS >= len) return;       // uniform exit

    __shared__ float Qs[BS * LDST];
    __shared__ float Ks[BS * LDST];
    __shared__ float Vs[BS * LDST];
    __shared__ float Ps[4][8][33];
    __shared__ unsigned Ms[BS];

    int tid = threadIdx.x;
    int w = tid >> 6, lane = tid & 63;
    int srow = tid >> 3, sc0 = tid & 7;            // staging: 8 threads/row

    // stage Q tile (rows qblk*32 + 0..31)
    {
        int mrow = qblk * BS + srow;
        int tok = o0 + (mrow < len ? mrow : len - 1);
        const float4* src = (const float4*)(q + (size_t)tok * HD + h * D);
        float4* dst = (float4*)(Qs + srow * LDST);
#pragma unroll
        for (int i = 0; i < 4; i++) dst[sc0 + 8 * i] = src[sc0 + 8 * i];
    }
    if (tid < BS) {
        int mrow = qblk * BS + tid;
        Ms[tid] = (mrow < len)
            ? selmask[(size_t)(b * H + h) * NMAX + mrow] : 0u;
    }
    __syncthreads();

    unsigned um = 0;
#pragma unroll
    for (int i = 0; i < BS; i++) um |= Ms[i];      // identical in all threads

    int mg = lane >> 4;                 // 0..3
    int jg = lane & 15;                 // 0..15
    int dg = lane & 15;                 // PV d-chunk [8dg, 8dg+8)
    int mloc0 = w * 8 + mg;             // tile-local query rows
    int mloc1 = mloc0 + 4;
    int mpos0 = qblk * BS + mloc0;
    int mpos1 = qblk * BS + mloc1;
    unsigned mask0 = Ms[mloc0], mask1 = Ms[mloc1];

    float Oa0[8], Oa1[8];
#pragma unroll
    for (int i = 0; i < 8; i++) { Oa0[i] = 0.f; Oa1[i] = 0.f; }

    while (um) {
        int kb = __builtin_ctz(um);
        um &= um - 1;
        __syncthreads();                // previous iter's readers done
        {   // stage K, V block kb
            int tok = o0 + kb * BS + srow;   // kb*BS+31 <= qblk*BS+31 < len
            const float4* ksrc = (const float4*)(k + (size_t)tok * HD + h * D);
            const float4* vsrc = (const float4*)(v + (size_t)tok * HD + h * D);
            float4* kdst = (float4*)(Ks + srow * LDST);
            float4* vdst = (float4*)(Vs + srow * LDST);
#pragma unroll
            for (int i = 0; i < 4; i++) {
                kdst[sc0 + 8 * i] = ksrc[sc0 + 8 * i];
                vdst[sc0 + 8 * i] = vsrc[sc0 + 8 * i];
            }
        }
        __syncthreads();

        // QK 2x2 micro-tile
        float s00 = 0.f, s01 = 0.f, s10 = 0.f, s11 = 0.f;
        const float4* q0 = (const float4*)(Qs + mloc0 * LDST);
        const float4* q1 = (const float4*)(Qs + mloc1 * LDST);
        const float4* k0 = (const float4*)(Ks + jg * LDST);
        const float4* k1 = (const float4*)(Ks + (jg + 16) * LDST);
#pragma unroll 8
        for (int d4 = 0; d4 < 32; d4++) {
            float4 a0 = q0[d4], a1 = q1[d4], b0 = k0[d4], b1 = k1[d4];
            s00 += a0.x * b0.x + a0.y * b0.y + a0.z * b0.z + a0.w * b0.w;
            s01 += a0.x * b1.x + a0.y * b1.y + a0.z * b1.z + a0.w * b1.w;
            s10 += a1.x * b0.x + a1.y * b0.y + a1.z * b0.z + a1.w * b0.w;
            s11 += a1.x * b1.x + a1.y * b1.y + a1.z * b1.z + a1.w * b1.w;
        }
        int kp0 = kb * BS + jg, kp1 = kb * BS + jg + 16;
        float p00 = ((mask0 >> kb) & 1u) && (kp0 <= mpos0) ? silu(s00 * SCALE) : 0.f;
        float p01 = ((mask0 >> kb) & 1u) && (kp1 <= mpos0) ? silu(s01 * SCALE) : 0.f;
        float p10 = ((mask1 >> kb) & 1u) && (kp0 <= mpos1) ? silu(s10 * SCALE) : 0.f;
        float p11 = ((mask1 >> kb) & 1u) && (kp1 <= mpos1) ? silu(s11 * SCALE) : 0.f;
        Ps[w][mg][jg]          = p00;
        Ps[w][mg][jg + 16]     = p01;
        Ps[w][mg + 4][jg]      = p10;
        Ps[w][mg + 4][jg + 16] = p11;
        // wave-private P tile: in-wave ds ordering via compiler lgkmcnt

        // PV: O rows {mg, mg+4}, d chunk [8dg, 8dg+8)
        const float* pr0 = &Ps[w][mg][0];
        const float* pr1 = &Ps[w][mg + 4][0];
#pragma unroll 4
        for (int j = 0; j < BS; j++) {
            float pa = pr0[j], pb = pr1[j];
            const float4* vrow = (const float4*)(Vs + j * LDST);
            float4 v0 = vrow[dg * 2], v1 = vrow[dg * 2 + 1];
            Oa0[0] += pa * v0.x; Oa0[1] += pa * v0.y;
            Oa0[2] += pa * v0.z; Oa0[3] += pa * v0.w;
            Oa0[4] += pa * v1.x; Oa0[5] += pa * v1.y;
            Oa0[6] += pa * v1.z; Oa0[7] += pa * v1.w;
            Oa1[0] += pb * v0.x; Oa1[1] += pb * v0.y;
            Oa1[2] += pb * v0.z; Oa1[3] += pb * v0.w;
            Oa1[4] += pb * v1.x; Oa1[5] += pb * v1.y;
            Oa1[6] += pb * v1.z; Oa1[7] += pb * v1.w;
        }
    }

    // epilogue: gate by g_slc, write jagged
    if (mpos0 < len) {
        float gs = g[(size_t)((b * NMAX + mpos0) * H + h) * 2 + 1];
        float* dst = o_slc_j + (size_t)(o0 + mpos0) * HD + h * D + dg * 8;
        float4 r0 = make_float4(Oa0[0] * gs, Oa0[1] * gs, Oa0[2] * gs, Oa0[3] * gs);
        float4 r1 = make_float4(Oa0[4] * gs, Oa0[5] * gs, Oa0[6] * gs, Oa0[7] * gs);
        *(float4*)dst = r0; *(float4*)(dst + 4) = r1;
    }
    if (mpos1 < len) {
        float gs = g[(size_t)((b * NMAX + mpos1) * H + h) * 2 + 1];
        float* dst = o_slc_j + (size_t)(o0 + mpos1) * HD + h * D + dg * 8;
        float4 r0 = make_float4(Oa1[0] * gs, Oa1[1] * gs, Oa1[2] * gs, Oa1[3] * gs);
        float4 r1 = make_float4(Oa1[4] * gs, Oa1[5] * gs, Oa1[6] * gs, Oa1[7] * gs);
        *(float4*)dst = r0; *(float4*)(dst + 4) = r1;
    }
}

// ---------------------------------------------------------------------------
// K6: LayerNorm(1024) per stream, gate by u, sum -> out (oc may alias out)
// ---------------------------------------------------------------------------
__global__ __launch_bounds__(256) void ln_combine_kernel(
    const float* __restrict__ oc, const float* __restrict__ os,
    const float* __restrict__ u, float* __restrict__ out) {
    int t = blockIdx.x, tid = threadIdx.x;
    size_t base = (size_t)t * HD;
    float4 xc = *(const float4*)(oc + base + tid * 4);
    float4 xs = *(const float4*)(os + base + tid * 4);
    float4 uu = *(const float4*)(u + base + tid * 4);
    float s_c = xc.x + xc.y + xc.z + xc.w;
    float q_c = xc.x * xc.x + xc.y * xc.y + xc.z * xc.z + xc.w * xc.w;
    float s_s = xs.x + xs.y + xs.z + xs.w;
    float q_s = xs.x * xs.x + xs.y * xs.y + xs.z * xs.z + xs.w * xs.w;
    s_c = wave_sum(s_c); q_c = wave_sum(q_c);
    s_s = wave_sum(s_s); q_s = wave_sum(q_s);
    __shared__ float red[4][4];
    int w = tid >> 6, lane = tid & 63;
    if (lane == 0) {
        red[w][0] = s_c; red[w][1] = q_c; red[w][2] = s_s; red[w][3] = q_s;
    }
    __syncthreads();
    float tsc = red[0][0] + red[1][0] + red[2][0] + red[3][0];
    float tqc = red[0][1] + red[1][1] + red[2][1] + red[3][1];
    float tss = red[0][2] + red[1][2] + red[2][2] + red[3][2];
    float tqs = red[0][3] + red[1][3] + red[2][3] + red[3][3];
    const float inv = 1.f / 1024.f;
    float mc = tsc * inv, vc = tqc * inv - mc * mc;
    float ms = tss * inv, vs = tqs * inv - ms * ms;
    float rc = rsqrtf(vc + 1e-5f), rs = rsqrtf(vs + 1e-5f);
    float4 o;
    o.x = ((xc.x - mc) * rc + (xs.x - ms) * rs) * uu.x;
    o.y = ((xc.y - mc) * rc + (xs.y - ms) * rs) * uu.y;
    o.z = ((xc.z - mc) * rc + (xs.z - ms) * rs) * uu.z;
    o.w = ((xc.w - mc) * rc + (xs.w - ms) * rs) * uu.w;
    *(float4*)(out + base + tid * 4) = o;
}

// ---------------------------------------------------------------------------
extern "C" void kernel_launch(void* const* d_in, const int* in_sizes, int n_in,
                              void* d_out, int out_size, void* d_ws, size_t ws_size,
                              hipStream_t stream) {
    const float* q  = (const float*)d_in[0];
    const float* k  = (const float*)d_in[1];
    const float* v  = (const float*)d_in[2];
    const float* u  = (const float*)d_in[3];
    const float* Wg = (const float*)d_in[4];
    const float* bg = (const float*)d_in[5];
    const int* offs = (const int*)d_in[6];   // int32 (jnp default, x64 off)

    int B = in_sizes[6] - 1;
    int T = in_sizes[0] / HD;

    float* out = (float*)d_out;
    float* qp  = out + (size_t)T * HD;
    float* kp  = qp + (size_t)B * NMAX * HD;

    float* o_cmp_j = out;   // aliases final out (safe: see ln_combine)

    char* w = (char*)d_ws;
    float* k_cmp = (float*)w;            w += (size_t)B * NB * HD * 4;
    float* v_cmp = (float*)w;            w += (size_t)B * NB * HD * 4;
    float* g     = (float*)w;            w += (size_t)B * NMAX * H * 2 * 4;
    unsigned* selmask = (unsigned*)w;    w += (size_t)B * H * NMAX * 4;
    float* o_slc_j = (float*)w;

    int padBlocks  = (B * NMAX * HD / 4) / 256;
    int cmpBlocks  = (B * NB * HD / 4) / 256;
    int gateBlocks = (B * NMAX * H) / 4;
    int attBlocks  = (B * H * NMAX) / 4;
    int selBlocks  = B * H * NB;                      // qblk-centric

    pad_qk_kernel<<<padBlocks, 256, 0, stream>>>(q, k, offs, qp, kp);
    compress_kernel<<<cmpBlocks, 256, 0, stream>>>(k, v, offs, k_cmp, v_cmp);
    gates_kernel<<<gateBlocks, 256, 0, stream>>>(q, Wg, bg, offs, g);
    cmp_attn_kernel<<<attBlocks, 256, 0, stream>>>(q, k_cmp, v_cmp, g, offs, o_cmp_j, selmask);
    sel_attn_v2<<<selBlocks, 256, 0, stream>>>(q, k, v, g, offs, selmask, o_slc_j);
    ln_combine_kernel<<<T, 256, 0, stream>>>(o_cmp_j, o_slc_j, u, out);
}

// Round 4
// 268.320 us; speedup vs baseline: 2.7394x; 1.6373x over previous
//
#include <hip/hip_runtime.h>
#include <cmath>

#define H 8
#define D 128
#define HD 1024            // H*D
#define NMAX 1024
#define BS 32
#define NB 32
#define S_SEL 8
#define SCALE 0.08838834764831845f   // 1/sqrt(128)
#define SENT -3.0e38f

typedef __attribute__((ext_vector_type(8))) short short8;   // 8 bf16 = 4 VGPRs
typedef __attribute__((ext_vector_type(4))) float f32x4;    // MFMA acc

#define MFMA16(a, b, c) __builtin_amdgcn_mfma_f32_16x16x32_bf16(a, b, c, 0, 0, 0)

__device__ __forceinline__ float wave_sum(float v) {
#pragma unroll
    for (int off = 32; off > 0; off >>= 1) v += __shfl_xor(v, off);
    return v;
}

__device__ __forceinline__ float silu(float x) {
    return x / (1.f + expf(-x));
}

// fp32 -> bf16 (round to nearest even), as raw bits
__device__ __forceinline__ unsigned short f2bf(float x) {
    unsigned u = __float_as_uint(x);
    return (unsigned short)((u + 0x7FFFu + ((u >> 16) & 1u)) >> 16);
}

// ---------------------------------------------------------------------------
// K1: write padded qp, kp into d_out (outputs 1 and 2)
// ---------------------------------------------------------------------------
__global__ __launch_bounds__(256) void pad_qk_kernel(
    const float* __restrict__ q, const float* __restrict__ k,
    const int* __restrict__ offs,
    float* __restrict__ qp, float* __restrict__ kp) {
    int idx = blockIdx.x * 256 + threadIdx.x;       // float4 index over [B,n,H,D/4]
    int d4 = idx & 31;
    int h  = (idx >> 5) & 7;
    int m  = (idx >> 8) & (NMAX - 1);
    int b  = idx >> 18;
    int o0 = offs[b];
    int len = offs[b + 1] - o0;
    float4 qv = make_float4(0.f, 0.f, 0.f, 0.f);
    float4 kv = qv;
    if (m < len) {
        size_t src = (size_t)(o0 + m) * HD + h * D + d4 * 4;
        qv = *(const float4*)(q + src);
        kv = *(const float4*)(k + src);
    }
    *(float4*)(qp + (size_t)idx * 4) = qv;
    *(float4*)(kp + (size_t)idx * 4) = kv;
}

// ---------------------------------------------------------------------------
// K2: block compression means
// ---------------------------------------------------------------------------
__global__ __launch_bounds__(256) void compress_kernel(
    const float* __restrict__ k, const float* __restrict__ v,
    const int* __restrict__ offs,
    float* __restrict__ k_cmp, float* __restrict__ v_cmp) {
    int idx = blockIdx.x * 256 + threadIdx.x;       // float4 index over [B,NB,H,D/4]
    int d4 = idx & 31;
    int h  = (idx >> 5) & 7;
    int kb = (idx >> 8) & (NB - 1);
    int b  = idx >> 13;
    int o0 = offs[b];
    int len = offs[b + 1] - o0;
    float4 ks = make_float4(0.f, 0.f, 0.f, 0.f);
    float4 vs = ks;
    int base = kb * BS;
#pragma unroll 4
    for (int j = 0; j < BS; j++) {
        int pos = base + j;
        if (pos < len) {
            size_t src = (size_t)(o0 + pos) * HD + h * D + d4 * 4;
            float4 kk = *(const float4*)(k + src);
            float4 vv = *(const float4*)(v + src);
            ks.x += kk.x; ks.y += kk.y; ks.z += kk.z; ks.w += kk.w;
            vs.x += vv.x; vs.y += vv.y; vs.z += vv.z; vs.w += vv.w;
        }
    }
    const float inv = 1.f / 32.f;
    ks.x *= inv; ks.y *= inv; ks.z *= inv; ks.w *= inv;
    vs.x *= inv; vs.y *= inv; vs.z *= inv; vs.w *= inv;
    *(float4*)(k_cmp + (size_t)idx * 4) = ks;
    *(float4*)(v_cmp + (size_t)idx * 4) = vs;
}

// ---------------------------------------------------------------------------
// K3: gates
// ---------------------------------------------------------------------------
__global__ __launch_bounds__(256) void gates_kernel(
    const float* __restrict__ q, const float* __restrict__ Wg,
    const float* __restrict__ bg, const int* __restrict__ offs,
    float* __restrict__ g) {
    int row  = blockIdx.x * 4 + (threadIdx.x >> 6);   // (b*N + m)*H + h
    int lane = threadIdx.x & 63;
    int h = row & 7;
    int m = (row >> 3) & (NMAX - 1);
    int b = row >> 13;
    int o0 = offs[b];
    int len = offs[b + 1] - o0;
    if (m >= len) return;
    size_t qb = (size_t)(o0 + m) * HD + h * D + lane * 2;
    float2 q2 = *(const float2*)(q + qb);
    int wb = (h * D + lane * 2) * 3;
    float p0 = q2.x * Wg[wb + 0] + q2.y * Wg[wb + 3];
    float p1 = q2.x * Wg[wb + 1] + q2.y * Wg[wb + 4];
    p0 = wave_sum(p0);
    p1 = wave_sum(p1);
    if (lane == 0) {
        float g0 = 1.f / (1.f + expf(-(p0 + bg[h * 3 + 0])));
        float g1 = 1.f / (1.f + expf(-(p1 + bg[h * 3 + 1])));
        float* gp = g + (size_t)row * 2;
        gp[0] = g0; gp[1] = g1;
    }
}

// ---------------------------------------------------------------------------
// K4: compressed attention + top-8 block selection -> bitmask
// one wave per (b,h,m) row
// ---------------------------------------------------------------------------
__global__ __launch_bounds__(256) void cmp_attn_kernel(
    const float* __restrict__ q, const float* __restrict__ k_cmp,
    const float* __restrict__ v_cmp, const float* __restrict__ g,
    const int* __restrict__ offs,
    float* __restrict__ o_cmp_j, unsigned* __restrict__ selmask) {
    int row  = blockIdx.x * 4 + (threadIdx.x >> 6);   // (b*H + h)*N + m
    int lane = threadIdx.x & 63;
    int m = row & (NMAX - 1);
    int h = (row >> 10) & 7;
    int b = row >> 13;
    int o0 = offs[b];
    int len = offs[b + 1] - o0;
    if (m >= len) return;
    int tok = o0 + m;
    float2 q2 = *(const float2*)(q + (size_t)tok * HD + h * D + lane * 2);
    int qblk = m >> 5;
    float myscore = SENT;                              // lane kb keeps score[kb]
    float2 acc = make_float2(0.f, 0.f);
    for (int kb = 0; kb <= qblk; kb++) {
        size_t cb = ((size_t)(b * NB + kb) * H + h) * D + lane * 2;
        float2 k2 = *(const float2*)(k_cmp + cb);
        float sc = wave_sum(q2.x * k2.x + q2.y * k2.y) * SCALE;
        if (lane == kb) myscore = sc;
        float p = silu(sc);
        float2 v2 = *(const float2*)(v_cmp + cb);
        acc.x += p * v2.x;
        acc.y += p * v2.y;
    }
    float gc = g[(size_t)((b * NMAX + m) * H + h) * 2];
    acc.x *= gc; acc.y *= gc;
    *(float2*)(o_cmp_j + (size_t)tok * HD + h * D + lane * 2) = acc;

    // top-8 (desc value, tie -> lower index) -> bitmask
    bool taken = false;
    unsigned mask = 0;
    for (int it = 0; it < S_SEL; it++) {
        float v = taken ? SENT : myscore;
        int idx = lane;
#pragma unroll
        for (int off = 32; off > 0; off >>= 1) {
            float ov = __shfl_xor(v, off);
            int oi = __shfl_xor(idx, off);
            if (ov > v || (ov == v && oi < idx)) { v = ov; idx = oi; }
        }
        if (v > -2.9e38f) {
            mask |= (1u << idx);
            if (idx == lane) taken = true;
        }
    }
    if (lane == 0) selmask[row] = mask;
}

// ---------------------------------------------------------------------------
// K5 v3: selected attention, qblk-centric, bf16 MFMA (16x16x32).
// One workgroup per (b,h,qblk). Q A-fragments live in registers (from global).
// Per union key-block: stage K row-major bf16 + V^T bf16 (conflict-free
// scatter), QK via MFMA (each wave one 16x16 S-quadrant), silu+mask -> P in
// LDS (A-layout round-trip, m120-verified), PV via MFMA (each wave a 32-wide
// d-slice, acc 2x2 tiles in VGPRs).
// Verified layouts: A[m=lane&15][k=quad*8+j]; C/D col=lane&15, row=quad*4+reg.
// ---------------------------------------------------------------------------
__global__ __launch_bounds__(256) void sel_attn_v3(
    const float* __restrict__ q, const float* __restrict__ k,
    const float* __restrict__ v, const float* __restrict__ g,
    const int* __restrict__ offs, const unsigned* __restrict__ selmask,
    float* __restrict__ o_slc_j) {
    int x = blockIdx.x;                 // ((b*H + h)*NB + qblk)
    int qblk = x & (NB - 1);
    int h = (x >> 5) & 7;
    int b = x >> 8;
    int o0 = offs[b];
    int len = offs[b + 1] - o0;
    if (qblk * BS >= len) return;       // uniform exit (len is a mult of 32)

    __shared__ __align__(16) unsigned short Ks[32 * 136];   // row-major, pad 8
    __shared__ __align__(16) unsigned short VTs[128 * 40];  // V^T [d][j], pad 8
    __shared__ __align__(16) unsigned short Ps[32 * 40];    // P [m][j], pad 8
    __shared__ unsigned Ms[BS];

    int tid = threadIdx.x;
    int w = tid >> 6, lane = tid & 63;
    int r = lane & 15, quad = lane >> 4;
    int mt = w >> 1, jt = w & 1;        // this wave's S-quadrant
    int stg_j = tid >> 3, stg_dc = tid & 7;   // staging: 8 threads per row

    if (tid < BS) {
        int mrow = qblk * BS + tid;
        Ms[tid] = (mrow < len) ? selmask[(size_t)(b * H + h) * NMAX + mrow] : 0u;
    }
    __syncthreads();
    unsigned um = 0;
#pragma unroll
    for (int i = 0; i < BS; i++) um |= Ms[i];   // identical across threads

    // Q A-fragments for this wave's m-tile, k-steps 0..3 (loop-invariant)
    short8 qf[4];
    {
        const float* qrow = q + (size_t)(o0 + qblk * BS + mt * 16 + r) * HD + h * D;
#pragma unroll
        for (int s = 0; s < 4; s++) {
            const float* p0 = qrow + s * 32 + quad * 8;
            float4 aa = *(const float4*)p0;
            float4 bb = *(const float4*)(p0 + 4);
            short8 f;
            f[0] = f2bf(aa.x); f[1] = f2bf(aa.y); f[2] = f2bf(aa.z); f[3] = f2bf(aa.w);
            f[4] = f2bf(bb.x); f[5] = f2bf(bb.y); f[6] = f2bf(bb.z); f[7] = f2bf(bb.w);
            qf[s] = f;
        }
    }

    f32x4 acc[2][2];                    // [m-tile][d-sub-tile]
#pragma unroll
    for (int a = 0; a < 2; a++)
#pragma unroll
        for (int c = 0; c < 2; c++) acc[a][c] = (f32x4){0.f, 0.f, 0.f, 0.f};

    while (um) {
        int kb = __builtin_ctz(um);
        um &= um - 1;
        __syncthreads();                // prev iter done reading Ks/VTs

        // stage K block (row-major bf16): coalesced float4 reads
        {
            const float* src = k + (size_t)(o0 + kb * BS + stg_j) * HD + h * D + stg_dc * 16;
            float4 f0 = *(const float4*)(src);
            float4 f1 = *(const float4*)(src + 4);
            float4 f2 = *(const float4*)(src + 8);
            float4 f3 = *(const float4*)(src + 12);
            short8 lo, hi;
            lo[0] = f2bf(f0.x); lo[1] = f2bf(f0.y); lo[2] = f2bf(f0.z); lo[3] = f2bf(f0.w);
            lo[4] = f2bf(f1.x); lo[5] = f2bf(f1.y); lo[6] = f2bf(f1.z); lo[7] = f2bf(f1.w);
            hi[0] = f2bf(f2.x); hi[1] = f2bf(f2.y); hi[2] = f2bf(f2.z); hi[3] = f2bf(f2.w);
            hi[4] = f2bf(f3.x); hi[5] = f2bf(f3.y); hi[6] = f2bf(f3.z); hi[7] = f2bf(f3.w);
            *(short8*)(Ks + stg_j * 136 + stg_dc * 16) = lo;
            *(short8*)(Ks + stg_j * 136 + stg_dc * 16 + 8) = hi;
        }
        // stage V^T (scatter; write banks (20*dc + j/2) mod 32: conflict-free)
        {
            const float* vbase = v + (size_t)(o0 + kb * BS + stg_j) * HD + h * D;
#pragma unroll
            for (int i = 0; i < 16; i++) {
                int d = stg_dc + 8 * i;
                VTs[d * 40 + stg_j] = f2bf(vbase[d]);
            }
        }
        __syncthreads();

        // QK: this wave's (mt, jt) 16x16 S-tile, K-dim 128 in 4 MFMA steps
        f32x4 sv = (f32x4){0.f, 0.f, 0.f, 0.f};
#pragma unroll
        for (int s = 0; s < 4; s++) {
            short8 kf = *(const short8*)(Ks + (jt * 16 + r) * 136 + s * 32 + quad * 8);
            sv = MFMA16(qf[s], kf, sv);
        }
        // silu + selection/causal mask -> P quadrant (bf16)
        int colj = jt * 16 + r;          // key index within block
        int kpos = kb * BS + colj;
#pragma unroll
        for (int i = 0; i < 4; i++) {
            int mrow = mt * 16 + quad * 4 + i;
            float p = (((Ms[mrow] >> kb) & 1u) && (kpos <= qblk * BS + mrow))
                      ? silu(sv[i] * SCALE) : 0.f;
            Ps[mrow * 40 + colj] = f2bf(p);
        }
        __syncthreads();

        // PV: this wave owns d-tiles {2w, 2w+1}; both m-tiles; K-dim 32
        short8 pf0 = *(const short8*)(Ps + r * 40 + quad * 8);
        short8 pf1 = *(const short8*)(Ps + (16 + r) * 40 + quad * 8);
        short8 vf0 = *(const short8*)(VTs + ((2 * w + 0) * 16 + r) * 40 + quad * 8);
        short8 vf1 = *(const short8*)(VTs + ((2 * w + 1) * 16 + r) * 40 + quad * 8);
        acc[0][0] = MFMA16(pf0, vf0, acc[0][0]);
        acc[0][1] = MFMA16(pf0, vf1, acc[0][1]);
        acc[1][0] = MFMA16(pf1, vf0, acc[1][0]);
        acc[1][1] = MFMA16(pf1, vf1, acc[1][1]);
    }

    // epilogue: gate by g_slc, write jagged (all 32 rows valid: len mult of 32)
#pragma unroll
    for (int mtl = 0; mtl < 2; mtl++) {
#pragma unroll
        for (int i = 0; i < 4; i++) {
            int mrow = mtl * 16 + quad * 4 + i;
            int gm = qblk * BS + mrow;
            float gs = g[(size_t)((b * NMAX + gm) * H + h) * 2 + 1];
            float* dst = o_slc_j + (size_t)(o0 + gm) * HD + h * D;
            dst[(2 * w + 0) * 16 + r] = acc[mtl][0][i] * gs;
            dst[(2 * w + 1) * 16 + r] = acc[mtl][1][i] * gs;
        }
    }
}

// ---------------------------------------------------------------------------
// K6: LayerNorm(1024) per stream, gate by u, sum -> out (oc may alias out)
// ---------------------------------------------------------------------------
__global__ __launch_bounds__(256) void ln_combine_kernel(
    const float* __restrict__ oc, const float* __restrict__ os,
    const float* __restrict__ u, float* __restrict__ out) {
    int t = blockIdx.x, tid = threadIdx.x;
    size_t base = (size_t)t * HD;
    float4 xc = *(const float4*)(oc + base + tid * 4);
    float4 xs = *(const float4*)(os + base + tid * 4);
    float4 uu = *(const float4*)(u + base + tid * 4);
    float s_c = xc.x + xc.y + xc.z + xc.w;
    float q_c = xc.x * xc.x + xc.y * xc.y + xc.z * xc.z + xc.w * xc.w;
    float s_s = xs.x + xs.y + xs.z + xs.w;
    float q_s = xs.x * xs.x + xs.y * xs.y + xs.z * xs.z + xs.w * xs.w;
    s_c = wave_sum(s_c); q_c = wave_sum(q_c);
    s_s = wave_sum(s_s); q_s = wave_sum(q_s);
    __shared__ float red[4][4];
    int w = tid >> 6, lane = tid & 63;
    if (lane == 0) {
        red[w][0] = s_c; red[w][1] = q_c; red[w][2] = s_s; red[w][3] = q_s;
    }
    __syncthreads();
    float tsc = red[0][0] + red[1][0] + red[2][0] + red[3][0];
    float tqc = red[0][1] + red[1][1] + red[2][1] + red[3][1];
    float tss = red[0][2] + red[1][2] + red[2][2] + red[3][2];
    float tqs = red[0][3] + red[1][3] + red[2][3] + red[3][3];
    const float inv = 1.f / 1024.f;
    float mc = tsc * inv, vc = tqc * inv - mc * mc;
    float ms = tss * inv, vs = tqs * inv - ms * ms;
    float rc = rsqrtf(vc + 1e-5f), rs = rsqrtf(vs + 1e-5f);
    float4 o;
    o.x = ((xc.x - mc) * rc + (xs.x - ms) * rs) * uu.x;
    o.y = ((xc.y - mc) * rc + (xs.y - ms) * rs) * uu.y;
    o.z = ((xc.z - mc) * rc + (xs.z - ms) * rs) * uu.z;
    o.w = ((xc.w - mc) * rc + (xs.w - ms) * rs) * uu.w;
    *(float4*)(out + base + tid * 4) = o;
}

// ---------------------------------------------------------------------------
extern "C" void kernel_launch(void* const* d_in, const int* in_sizes, int n_in,
                              void* d_out, int out_size, void* d_ws, size_t ws_size,
                              hipStream_t stream) {
    const float* q  = (const float*)d_in[0];
    const float* k  = (const float*)d_in[1];
    const float* v  = (const float*)d_in[2];
    const float* u  = (const float*)d_in[3];
    const float* Wg = (const float*)d_in[4];
    const float* bg = (const float*)d_in[5];
    const int* offs = (const int*)d_in[6];   // int32 (jnp default, x64 off)

    int B = in_sizes[6] - 1;
    int T = in_sizes[0] / HD;

    float* out = (float*)d_out;
    float* qp  = out + (size_t)T * HD;
    float* kp  = qp + (size_t)B * NMAX * HD;

    float* o_cmp_j = out;   // aliases final out (safe: see ln_combine)

    char* w = (char*)d_ws;
    float* k_cmp = (float*)w;            w += (size_t)B * NB * HD * 4;
    float* v_cmp = (float*)w;            w += (size_t)B * NB * HD * 4;
    float* g     = (float*)w;            w += (size_t)B * NMAX * H * 2 * 4;
    unsigned* selmask = (unsigned*)w;    w += (size_t)B * H * NMAX * 4;
    float* o_slc_j = (float*)w;

    int padBlocks  = (B * NMAX * HD / 4) / 256;
    int cmpBlocks  = (B * NB * HD / 4) / 256;
    int gateBlocks = (B * NMAX * H) / 4;
    int attBlocks  = (B * H * NMAX) / 4;
    int selBlocks  = B * H * NB;                      // qblk-centric

    pad_qk_kernel<<<padBlocks, 256, 0, stream>>>(q, k, offs, qp, kp);
    compress_kernel<<<cmpBlocks, 256, 0, stream>>>(k, v, offs, k_cmp, v_cmp);
    gates_kernel<<<gateBlocks, 256, 0, stream>>>(q, Wg, bg, offs, g);
    cmp_attn_kernel<<<attBlocks, 256, 0, stream>>>(q, k_cmp, v_cmp, g, offs, o_cmp_j, selmask);
    sel_attn_v3<<<selBlocks, 256, 0, stream>>>(q, k, v, g, offs, selmask, o_slc_j);
    ln_combine_kernel<<<T, 256, 0, stream>>>(o_cmp_j, o_slc_j, u, out);
}

// Round 6
// 248.092 us; speedup vs baseline: 2.9628x; 1.0815x over previous
//
#include <hip/hip_runtime.h>
#include <hip/hip_bf16.h>
#include <cmath>

#define H 8
#define D 128
#define HD 1024            // H*D
#define NMAX 1024
#define BS 32
#define NB 32
#define S_SEL 8
#define SCALE 0.08838834764831845f   // 1/sqrt(128)
#define SENT -3.0e38f

typedef __attribute__((ext_vector_type(8))) short short8;   // 8 bf16 = 4 VGPRs
typedef __attribute__((ext_vector_type(4))) float f32x4;    // MFMA acc

#define MFMA16(a, b, c) __builtin_amdgcn_mfma_f32_16x16x32_bf16(a, b, c, 0, 0, 0)

__device__ __forceinline__ float silu(float x) {
    return x / (1.f + expf(-x));
}

// fp32 -> bf16 raw bits (native cvt, RTNE)
__device__ __forceinline__ unsigned short f2bf(float x) {
    return __builtin_bit_cast(unsigned short, __float2bfloat16(x));
}
__device__ __forceinline__ float bfup(unsigned short b) {
    unsigned u = (unsigned)b << 16;
    return __builtin_bit_cast(float, u);
}
// 3-term bf16 split: x ~= b0 + b1 + b2 with |err| ~ 2^-27 |x|
__device__ __forceinline__ void split3(float x, unsigned short& b0,
                                       unsigned short& b1, unsigned short& b2) {
    b0 = f2bf(x);
    float r1 = x - bfup(b0);
    b1 = f2bf(r1);
    float r2 = r1 - bfup(b1);
    b2 = f2bf(r2);
}

// ---------------------------------------------------------------------------
// K1: padded qp, kp (outputs 1,2) + fused gate computation.
// ---------------------------------------------------------------------------
__global__ __launch_bounds__(256) void pad_gates_kernel(
    const float* __restrict__ q, const float* __restrict__ k,
    const float* __restrict__ Wg, const float* __restrict__ bg,
    const int* __restrict__ offs,
    float* __restrict__ qp, float* __restrict__ kp, float* __restrict__ g) {
    int idx = blockIdx.x * 256 + threadIdx.x;       // float4 index over [B,n,H,D/4]
    int d4 = idx & 31;
    int h  = (idx >> 5) & 7;
    int m  = (idx >> 8) & (NMAX - 1);
    int b  = idx >> 18;
    int o0 = offs[b];
    int len = offs[b + 1] - o0;
    float4 qv = make_float4(0.f, 0.f, 0.f, 0.f);
    float4 kv = qv;
    if (m < len) {
        size_t src = (size_t)(o0 + m) * HD + h * D + d4 * 4;
        qv = *(const float4*)(q + src);
        kv = *(const float4*)(k + src);
    }
    *(float4*)(qp + (size_t)idx * 4) = qv;
    *(float4*)(kp + (size_t)idx * 4) = kv;

    // gates: per-(b,m,h) dot(q, Wg[h,:,e]) over half-wave (32 lanes share row)
    int wb = (h * D + d4 * 4) * 3;                  // Wg[h,d,e] at (h*D+d)*3+e
    float p0 = qv.x * Wg[wb + 0] + qv.y * Wg[wb + 3]
             + qv.z * Wg[wb + 6] + qv.w * Wg[wb + 9];
    float p1 = qv.x * Wg[wb + 1] + qv.y * Wg[wb + 4]
             + qv.z * Wg[wb + 7] + qv.w * Wg[wb + 10];
#pragma unroll
    for (int off = 16; off > 0; off >>= 1) {
        p0 += __shfl_xor(p0, off);
        p1 += __shfl_xor(p1, off);
    }
    if (d4 == 0) {
        float g0 = 1.f / (1.f + expf(-(p0 + bg[h * 3 + 0])));
        float g1 = 1.f / (1.f + expf(-(p1 + bg[h * 3 + 1])));
        float* gp = g + (size_t)((b * NMAX + m) * H + h) * 2;
        gp[0] = g0; gp[1] = g1;
    }
}

// ---------------------------------------------------------------------------
// K2: block compression means
// ---------------------------------------------------------------------------
__global__ __launch_bounds__(256) void compress_kernel(
    const float* __restrict__ k, const float* __restrict__ v,
    const int* __restrict__ offs,
    float* __restrict__ k_cmp, float* __restrict__ v_cmp) {
    int idx = blockIdx.x * 256 + threadIdx.x;       // float4 index over [B,NB,H,D/4]
    int d4 = idx & 31;
    int h  = (idx >> 5) & 7;
    int kb = (idx >> 8) & (NB - 1);
    int b  = idx >> 13;
    int o0 = offs[b];
    int len = offs[b + 1] - o0;
    float4 ks = make_float4(0.f, 0.f, 0.f, 0.f);
    float4 vs = ks;
    int base = kb * BS;
#pragma unroll 4
    for (int j = 0; j < BS; j++) {
        int pos = base + j;
        if (pos < len) {
            size_t src = (size_t)(o0 + pos) * HD + h * D + d4 * 4;
            float4 kk = *(const float4*)(k + src);
            float4 vv = *(const float4*)(v + src);
            ks.x += kk.x; ks.y += kk.y; ks.z += kk.z; ks.w += kk.w;
            vs.x += vv.x; vs.y += vv.y; vs.z += vv.z; vs.w += vv.w;
        }
    }
    const float inv = 1.f / 32.f;
    ks.x *= inv; ks.y *= inv; ks.z *= inv; ks.w *= inv;
    vs.x *= inv; vs.y *= inv; vs.z *= inv; vs.w *= inv;
    *(float4*)(k_cmp + (size_t)idx * 4) = ks;
    *(float4*)(v_cmp + (size_t)idx * 4) = vs;
}

// ---------------------------------------------------------------------------
// K3: FUSED attention per (b,h,qblk) tile.
// Phase C: compressed QK via 3-term split-bf16 MFMA (fp32-equivalent scores
//   for top-8 selection — bf16 scores flip selections, R5 post-mortem),
//   silu P -> o_cmp PV (bf16 MFMA).
// Selection: qblk<8 -> constant mask; else 32-lane butterfly on fp32 scores.
// Phase S: while-loop over union mask: stage K/V block, QK, mask+silu, PV.
// MFMA layouts (m89/m120, R4-verified end-to-end): A[m=lane&15][k=quad*8+j];
//   C/D col=lane&15, row=quad*4+reg.
// ---------------------------------------------------------------------------
__global__ __launch_bounds__(256) void fused_attn(
    const float* __restrict__ q, const float* __restrict__ k,
    const float* __restrict__ v, const float* __restrict__ k_cmp,
    const float* __restrict__ v_cmp, const float* __restrict__ g,
    const int* __restrict__ offs,
    float* __restrict__ o_cmp_j, float* __restrict__ o_slc_j) {
    int x = blockIdx.x;                 // ((b*H + h)*NB + qblk)
    int qblk = x & (NB - 1);
    int h = (x >> 5) & 7;
    int b = x >> 8;
    int o0 = offs[b];
    int len = offs[b + 1] - o0;
    if (qblk * BS >= len) return;       // uniform exit (len is mult of 32)

    __shared__ __align__(16) unsigned short Ks0[32 * 136];  // plane 0 / phase-S K
    __shared__ __align__(16) unsigned short Ks1[32 * 136];  // split plane 1
    __shared__ __align__(16) unsigned short Ks2[32 * 136];  // split plane 2
    __shared__ __align__(16) unsigned short VTs[128 * 40];  // V^T [d][j]
    __shared__ __align__(16) unsigned short Ps[32 * 40];    // P [m][j]
    __shared__ float Ss[32 * 33];                           // fp32 scores
    __shared__ unsigned Ms[BS];

    int tid = threadIdx.x;
    int w = tid >> 6, lane = tid & 63;
    int r = lane & 15, quad = lane >> 4;
    int mt = w >> 1, jt = w & 1;        // this wave's S-quadrant
    int stg_j = tid >> 3, stg_dc = tid & 7;   // staging: 8 threads per row

    // Q fragments: 3 split planes (loop-invariant, registers)
    short8 qf0[4], qf1[4], qf2[4];
    {
        const float* qrow = q + (size_t)(o0 + qblk * BS + mt * 16 + r) * HD + h * D;
#pragma unroll
        for (int s = 0; s < 4; s++) {
            const float* p0 = qrow + s * 32 + quad * 8;
            float xv[8];
            *(float4*)(xv) = *(const float4*)p0;
            *(float4*)(xv + 4) = *(const float4*)(p0 + 4);
            short8 f0, f1, f2;
#pragma unroll
            for (int i = 0; i < 8; i++) {
                unsigned short e0, e1, e2;
                split3(xv[i], e0, e1, e2);
                f0[i] = (short)e0; f1[i] = (short)e1; f2[i] = (short)e2;
            }
            qf0[s] = f0; qf1[s] = f1; qf2[s] = f2;
        }
    }

    f32x4 accC[2][2], accS[2][2];
#pragma unroll
    for (int a = 0; a < 2; a++)
#pragma unroll
        for (int c = 0; c < 2; c++) {
            accC[a][c] = (f32x4){0.f, 0.f, 0.f, 0.f};
            accS[a][c] = (f32x4){0.f, 0.f, 0.f, 0.f};
        }

    // ---- phase C: stage k_cmp (3 planes) + v_cmp^T ----
    {
        const float* src = k_cmp + ((size_t)(b * NB + stg_j) * H + h) * D + stg_dc * 16;
        float xv[16];
        *(float4*)(xv + 0)  = *(const float4*)(src);
        *(float4*)(xv + 4)  = *(const float4*)(src + 4);
        *(float4*)(xv + 8)  = *(const float4*)(src + 8);
        *(float4*)(xv + 12) = *(const float4*)(src + 12);
        short8 a0, a1, a2, b0, b1, b2;
#pragma unroll
        for (int i = 0; i < 8; i++) {
            unsigned short e0, e1, e2;
            split3(xv[i], e0, e1, e2);
            a0[i] = (short)e0; a1[i] = (short)e1; a2[i] = (short)e2;
            split3(xv[8 + i], e0, e1, e2);
            b0[i] = (short)e0; b1[i] = (short)e1; b2[i] = (short)e2;
        }
        int ofs = stg_j * 136 + stg_dc * 16;
        *(short8*)(Ks0 + ofs) = a0; *(short8*)(Ks0 + ofs + 8) = b0;
        *(short8*)(Ks1 + ofs) = a1; *(short8*)(Ks1 + ofs + 8) = b1;
        *(short8*)(Ks2 + ofs) = a2; *(short8*)(Ks2 + ofs + 8) = b2;
        const float* vbase = v_cmp + ((size_t)(b * NB + stg_j) * H + h) * D;
#pragma unroll
        for (int i = 0; i < 16; i++) {
            int d = stg_dc + 8 * i;
            VTs[d * 40 + stg_j] = f2bf(vbase[d]);
        }
    }
    __syncthreads();

    // compressed QK: 6 product rounds (small terms first), one fp32 acc chain
    {
        f32x4 sv = (f32x4){0.f, 0.f, 0.f, 0.f};
#pragma unroll
        for (int s = 0; s < 4; s++) {
            int ofs = (jt * 16 + r) * 136 + s * 32 + quad * 8;
            short8 k0 = *(const short8*)(Ks0 + ofs);
            short8 k1 = *(const short8*)(Ks1 + ofs);
            short8 k2 = *(const short8*)(Ks2 + ofs);
            sv = MFMA16(qf1[s], k1, sv);    // q1*k1  (~2^-18)
            sv = MFMA16(qf0[s], k2, sv);    // q0*k2  (~2^-18)
            sv = MFMA16(qf2[s], k0, sv);    // q2*k0  (~2^-18)
            sv = MFMA16(qf0[s], k1, sv);    // q0*k1  (~2^-9)
            sv = MFMA16(qf1[s], k0, sv);    // q1*k0  (~2^-9)
            sv = MFMA16(qf0[s], k0, sv);    // q0*k0
        }
        int colj = jt * 16 + r;             // compressed block index kb
        bool causal = (colj <= qblk);       // same bound for all rows of tile
#pragma unroll
        for (int i = 0; i < 4; i++) {
            int mrow = mt * 16 + quad * 4 + i;
            float sc = sv[i] * SCALE;
            Ss[mrow * 33 + colj] = causal ? sc : SENT;
            Ps[mrow * 40 + colj] = f2bf(causal ? silu(sc) : 0.f);
        }
    }
    __syncthreads();

    // compressed PV
    {
        short8 pf0 = *(const short8*)(Ps + r * 40 + quad * 8);
        short8 pf1 = *(const short8*)(Ps + (16 + r) * 40 + quad * 8);
        short8 vf0 = *(const short8*)(VTs + ((2 * w + 0) * 16 + r) * 40 + quad * 8);
        short8 vf1 = *(const short8*)(VTs + ((2 * w + 1) * 16 + r) * 40 + quad * 8);
        accC[0][0] = MFMA16(pf0, vf0, accC[0][0]);
        accC[0][1] = MFMA16(pf0, vf1, accC[0][1]);
        accC[1][0] = MFMA16(pf1, vf0, accC[1][0]);
        accC[1][1] = MFMA16(pf1, vf1, accC[1][1]);
    }

    // selection -> Ms (fp32 scores)
    if (qblk < S_SEL) {
        if (tid < BS) Ms[tid] = (1u << (qblk + 1)) - 1u;
    } else {
        int h2 = lane >> 5, l32 = lane & 31;
#pragma unroll
        for (int pass = 0; pass < 4; pass++) {
            int row = w * 8 + pass * 2 + h2;
            float val = Ss[row * 33 + l32];
            unsigned mask = 0;
            bool taken = false;
            for (int it = 0; it < S_SEL; it++) {
                float vv = taken ? SENT : val;
                int idx = l32;
#pragma unroll
                for (int off = 16; off > 0; off >>= 1) {
                    float ov = __shfl_xor(vv, off);
                    int oi = __shfl_xor(idx, off);
                    if (ov > vv || (ov == vv && oi < idx)) { vv = ov; idx = oi; }
                }
                if (vv > -2.9e38f) {
                    mask |= (1u << idx);
                    if (idx == l32) taken = true;
                }
            }
            if (l32 == 0) Ms[row] = mask;
        }
    }
    __syncthreads();

    unsigned um = 0;
#pragma unroll
    for (int i = 0; i < BS; i++) um |= Ms[i];   // identical across threads

    // ---- phase S: selected blocks ----
    while (um) {
        int kb = __builtin_ctz(um);
        um &= um - 1;
        __syncthreads();                // prior readers of Ks0/VTs/Ps done
        {   // stage K (row-major bf16, plane 0) + V^T from jagged k, v
            const float* src = k + (size_t)(o0 + kb * BS + stg_j) * HD + h * D + stg_dc * 16;
            float4 f0 = *(const float4*)(src);
            float4 f1 = *(const float4*)(src + 4);
            float4 f2 = *(const float4*)(src + 8);
            float4 f3 = *(const float4*)(src + 12);
            short8 lo, hi;
            lo[0] = f2bf(f0.x); lo[1] = f2bf(f0.y); lo[2] = f2bf(f0.z); lo[3] = f2bf(f0.w);
            lo[4] = f2bf(f1.x); lo[5] = f2bf(f1.y); lo[6] = f2bf(f1.z); lo[7] = f2bf(f1.w);
            hi[0] = f2bf(f2.x); hi[1] = f2bf(f2.y); hi[2] = f2bf(f2.z); hi[3] = f2bf(f2.w);
            hi[4] = f2bf(f3.x); hi[5] = f2bf(f3.y); hi[6] = f2bf(f3.z); hi[7] = f2bf(f3.w);
            *(short8*)(Ks0 + stg_j * 136 + stg_dc * 16) = lo;
            *(short8*)(Ks0 + stg_j * 136 + stg_dc * 16 + 8) = hi;
            const float* vbase = v + (size_t)(o0 + kb * BS + stg_j) * HD + h * D;
#pragma unroll
            for (int i = 0; i < 16; i++) {
                int d = stg_dc + 8 * i;
                VTs[d * 40 + stg_j] = f2bf(vbase[d]);
            }
        }
        __syncthreads();

        // QK
        f32x4 sv = (f32x4){0.f, 0.f, 0.f, 0.f};
#pragma unroll
        for (int s = 0; s < 4; s++) {
            short8 kf = *(const short8*)(Ks0 + (jt * 16 + r) * 136 + s * 32 + quad * 8);
            sv = MFMA16(qf0[s], kf, sv);
        }
        int colj = jt * 16 + r;
        int kpos = kb * BS + colj;
#pragma unroll
        for (int i = 0; i < 4; i++) {
            int mrow = mt * 16 + quad * 4 + i;
            float p = (((Ms[mrow] >> kb) & 1u) && (kpos <= qblk * BS + mrow))
                      ? silu(sv[i] * SCALE) : 0.f;
            Ps[mrow * 40 + colj] = f2bf(p);
        }
        __syncthreads();                // Ps visible cross-wave

        // PV
        short8 pf0 = *(const short8*)(Ps + r * 40 + quad * 8);
        short8 pf1 = *(const short8*)(Ps + (16 + r) * 40 + quad * 8);
        short8 vf0 = *(const short8*)(VTs + ((2 * w + 0) * 16 + r) * 40 + quad * 8);
        short8 vf1 = *(const short8*)(VTs + ((2 * w + 1) * 16 + r) * 40 + quad * 8);
        accS[0][0] = MFMA16(pf0, vf0, accS[0][0]);
        accS[0][1] = MFMA16(pf0, vf1, accS[0][1]);
        accS[1][0] = MFMA16(pf1, vf0, accS[1][0]);
        accS[1][1] = MFMA16(pf1, vf1, accS[1][1]);
    }

    // epilogue: gate both streams, write jagged
#pragma unroll
    for (int mtl = 0; mtl < 2; mtl++) {
#pragma unroll
        for (int i = 0; i < 4; i++) {
            int mrow = mtl * 16 + quad * 4 + i;
            int gm = qblk * BS + mrow;
            float2 g2 = *(const float2*)(g + (size_t)((b * NMAX + gm) * H + h) * 2);
            size_t dbase = (size_t)(o0 + gm) * HD + h * D;
            float* dc = o_cmp_j + dbase;
            float* ds = o_slc_j + dbase;
            dc[(2 * w + 0) * 16 + r] = accC[mtl][0][i] * g2.x;
            dc[(2 * w + 1) * 16 + r] = accC[mtl][1][i] * g2.x;
            ds[(2 * w + 0) * 16 + r] = accS[mtl][0][i] * g2.y;
            ds[(2 * w + 1) * 16 + r] = accS[mtl][1][i] * g2.y;
        }
    }
}

// ---------------------------------------------------------------------------
// K4: LayerNorm(1024) per stream, gate by u, sum -> out (oc may alias out)
// ---------------------------------------------------------------------------
__global__ __launch_bounds__(256) void ln_combine_kernel(
    const float* __restrict__ oc, const float* __restrict__ os,
    const float* __restrict__ u, float* __restrict__ out) {
    int t = blockIdx.x, tid = threadIdx.x;
    size_t base = (size_t)t * HD;
    float4 xc = *(const float4*)(oc + base + tid * 4);
    float4 xs = *(const float4*)(os + base + tid * 4);
    float4 uu = *(const float4*)(u + base + tid * 4);
    float s_c = xc.x + xc.y + xc.z + xc.w;
    float q_c = xc.x * xc.x + xc.y * xc.y + xc.z * xc.z + xc.w * xc.w;
    float s_s = xs.x + xs.y + xs.z + xs.w;
    float q_s = xs.x * xs.x + xs.y * xs.y + xs.z * xs.z + xs.w * xs.w;
#pragma unroll
    for (int off = 32; off > 0; off >>= 1) {
        s_c += __shfl_xor(s_c, off); q_c += __shfl_xor(q_c, off);
        s_s += __shfl_xor(s_s, off); q_s += __shfl_xor(q_s, off);
    }
    __shared__ float red[4][4];
    int w = tid >> 6, lane = tid & 63;
    if (lane == 0) {
        red[w][0] = s_c; red[w][1] = q_c; red[w][2] = s_s; red[w][3] = q_s;
    }
    __syncthreads();
    float tsc = red[0][0] + red[1][0] + red[2][0] + red[3][0];
    float tqc = red[0][1] + red[1][1] + red[2][1] + red[3][1];
    float tss = red[0][2] + red[1][2] + red[2][2] + red[3][2];
    float tqs = red[0][3] + red[1][3] + red[2][3] + red[3][3];
    const float inv = 1.f / 1024.f;
    float mc = tsc * inv, vc = tqc * inv - mc * mc;
    float ms = tss * inv, vs = tqs * inv - ms * ms;
    float rc = rsqrtf(vc + 1e-5f), rs = rsqrtf(vs + 1e-5f);
    float4 o;
    o.x = ((xc.x - mc) * rc + (xs.x - ms) * rs) * uu.x;
    o.y = ((xc.y - mc) * rc + (xs.y - ms) * rs) * uu.y;
    o.z = ((xc.z - mc) * rc + (xs.z - ms) * rs) * uu.z;
    o.w = ((xc.w - mc) * rc + (xs.w - ms) * rs) * uu.w;
    *(float4*)(out + base + tid * 4) = o;
}

// ---------------------------------------------------------------------------
extern "C" void kernel_launch(void* const* d_in, const int* in_sizes, int n_in,
                              void* d_out, int out_size, void* d_ws, size_t ws_size,
                              hipStream_t stream) {
    const float* q  = (const float*)d_in[0];
    const float* k  = (const float*)d_in[1];
    const float* v  = (const float*)d_in[2];
    const float* u  = (const float*)d_in[3];
    const float* Wg = (const float*)d_in[4];
    const float* bg = (const float*)d_in[5];
    const int* offs = (const int*)d_in[6];   // int32 (jnp default, x64 off)

    int B = in_sizes[6] - 1;
    int T = in_sizes[0] / HD;

    float* out = (float*)d_out;
    float* qp  = out + (size_t)T * HD;
    float* kp  = qp + (size_t)B * NMAX * HD;

    float* o_cmp_j = out;   // aliases final out (safe: see ln_combine)

    char* w = (char*)d_ws;
    float* k_cmp = (float*)w;            w += (size_t)B * NB * HD * 4;
    float* v_cmp = (float*)w;            w += (size_t)B * NB * HD * 4;
    float* g     = (float*)w;            w += (size_t)B * NMAX * H * 2 * 4;
    float* o_slc_j = (float*)w;

    int padBlocks  = (B * NMAX * HD / 4) / 256;
    int cmpBlocks  = (B * NB * HD / 4) / 256;
    int fusBlocks  = B * H * NB;

    pad_gates_kernel<<<padBlocks, 256, 0, stream>>>(q, k, Wg, bg, offs, qp, kp, g);
    compress_kernel<<<cmpBlocks, 256, 0, stream>>>(k, v, offs, k_cmp, v_cmp);
    fused_attn<<<fusBlocks, 256, 0, stream>>>(q, k, v, k_cmp, v_cmp, g, offs,
                                              o_cmp_j, o_slc_j);
    ln_combine_kernel<<<T, 256, 0, stream>>>(o_cmp_j, o_slc_j, u, out);
}

// Round 7
// 246.218 us; speedup vs baseline: 2.9854x; 1.0076x over previous
//
#include <hip/hip_runtime.h>
#include <hip/hip_bf16.h>
#include <cmath>

#define H 8
#define D 128
#define HD 1024            // H*D
#define NMAX 1024
#define BS 32
#define NB 32
#define S_SEL 8
#define SCALE 0.08838834764831845f   // 1/sqrt(128)
#define SENT -3.0e38f

typedef __attribute__((ext_vector_type(8))) short short8;   // 8 bf16 = 4 VGPRs
typedef __attribute__((ext_vector_type(4))) float f32x4;    // MFMA acc

#define MFMA16(a, b, c) __builtin_amdgcn_mfma_f32_16x16x32_bf16(a, b, c, 0, 0, 0)

__device__ __forceinline__ float silu(float x) {
    return x / (1.f + expf(-x));
}
__device__ __forceinline__ unsigned short f2bf(float x) {
    return __builtin_bit_cast(unsigned short, __float2bfloat16(x));
}
__device__ __forceinline__ float bfup(unsigned short b) {
    unsigned u = (unsigned)b << 16;
    return __builtin_bit_cast(float, u);
}
// 3-term bf16 split: x ~= b0 + b1 + b2 with |err| ~ 2^-27 |x|
__device__ __forceinline__ void split3(float x, unsigned short& b0,
                                       unsigned short& b1, unsigned short& b2) {
    b0 = f2bf(x);
    float r1 = x - bfup(b0);
    b1 = f2bf(r1);
    float r2 = r1 - bfup(b1);
    b2 = f2bf(r2);
}

// ---------------------------------------------------------------------------
// K1 prep: per (b,h,nt) 32-token block:
//   - kb16[tok][h][d]   : bf16 copy of K (straight convert, coalesced)
//   - vt_blk[bh][nt][d][j]: bf16 V^T in 8KB contiguous blocks (LDS transpose)
//   - g[b,m,h,{0,1}]    : gates (8-lane reduction, lanes share (tok,h))
// ---------------------------------------------------------------------------
__global__ __launch_bounds__(256) void prep_kernel(
    const float* __restrict__ q, const float* __restrict__ k,
    const float* __restrict__ v, const float* __restrict__ Wg,
    const float* __restrict__ bg, const int* __restrict__ offs,
    unsigned short* __restrict__ kb16, unsigned short* __restrict__ vt_blk,
    float* __restrict__ g) {
    int x = blockIdx.x;
    int nt = x & (NB - 1);
    int h = (x >> 5) & 7;
    int b = x >> 8;
    int o0 = offs[b];
    int len = offs[b + 1] - o0;
    if (nt * BS >= len) return;

    __shared__ __align__(16) unsigned short tile[128 * 40];
    int tid = threadIdx.x;
    int j = tid >> 3, dc = tid & 7;
    size_t base = (size_t)(o0 + nt * BS + j) * HD + h * D + dc * 16;

    // K -> kb16 (bf16, same layout)
    {
        float xv[16];
        *(float4*)(xv + 0)  = *(const float4*)(k + base);
        *(float4*)(xv + 4)  = *(const float4*)(k + base + 4);
        *(float4*)(xv + 8)  = *(const float4*)(k + base + 8);
        *(float4*)(xv + 12) = *(const float4*)(k + base + 12);
        short8 lo, hi;
#pragma unroll
        for (int i = 0; i < 8; i++) { lo[i] = (short)f2bf(xv[i]); hi[i] = (short)f2bf(xv[8 + i]); }
        *(short8*)(kb16 + base) = lo;
        *(short8*)(kb16 + base + 8) = hi;
    }
    // V -> LDS transpose tile[d][j]
    {
        float xv[16];
        *(float4*)(xv + 0)  = *(const float4*)(v + base);
        *(float4*)(xv + 4)  = *(const float4*)(v + base + 4);
        *(float4*)(xv + 8)  = *(const float4*)(v + base + 8);
        *(float4*)(xv + 12) = *(const float4*)(v + base + 12);
#pragma unroll
        for (int i = 0; i < 16; i++) tile[(dc * 16 + i) * 40 + j] = f2bf(xv[i]);
    }
    // gates (dot over this thread's 16 dims, reduce across 8 dc-lanes)
    {
        float xv[16];
        *(float4*)(xv + 0)  = *(const float4*)(q + base);
        *(float4*)(xv + 4)  = *(const float4*)(q + base + 4);
        *(float4*)(xv + 8)  = *(const float4*)(q + base + 8);
        *(float4*)(xv + 12) = *(const float4*)(q + base + 12);
        float p0 = 0.f, p1 = 0.f;
#pragma unroll
        for (int i = 0; i < 16; i++) {
            int wb = (h * D + dc * 16 + i) * 3;
            p0 += xv[i] * Wg[wb + 0];
            p1 += xv[i] * Wg[wb + 1];
        }
#pragma unroll
        for (int off = 4; off > 0; off >>= 1) {
            p0 += __shfl_xor(p0, off);
            p1 += __shfl_xor(p1, off);
        }
        if (dc == 0) {
            float g0 = 1.f / (1.f + expf(-(p0 + bg[h * 3 + 0])));
            float g1 = 1.f / (1.f + expf(-(p1 + bg[h * 3 + 1])));
            float* gp = g + (size_t)((b * NMAX + nt * BS + j) * H + h) * 2;
            gp[0] = g0; gp[1] = g1;
        }
    }
    __syncthreads();
    // tile -> vt_blk (contiguous 8KB per (bh,nt))
    {
        int d = tid >> 1, hf = tid & 1;
        short8 a = *(const short8*)(tile + d * 40 + hf * 16);
        short8 c = *(const short8*)(tile + d * 40 + hf * 16 + 8);
        size_t ob = ((size_t)((b * H + h) * NB + nt) * 128 + d) * 32 + hf * 16;
        *(short8*)(vt_blk + ob) = a;
        *(short8*)(vt_blk + ob + 8) = c;
    }
}

// ---------------------------------------------------------------------------
// K2: block compression means (fp32 — selection precision depends on it)
// ---------------------------------------------------------------------------
__global__ __launch_bounds__(256) void compress_kernel(
    const float* __restrict__ k, const float* __restrict__ v,
    const int* __restrict__ offs,
    float* __restrict__ k_cmp, float* __restrict__ v_cmp) {
    int idx = blockIdx.x * 256 + threadIdx.x;       // float4 index over [B,NB,H,D/4]
    int d4 = idx & 31;
    int h  = (idx >> 5) & 7;
    int kb = (idx >> 8) & (NB - 1);
    int b  = idx >> 13;
    int o0 = offs[b];
    int len = offs[b + 1] - o0;
    float4 ks = make_float4(0.f, 0.f, 0.f, 0.f);
    float4 vs = ks;
    int base = kb * BS;
#pragma unroll 4
    for (int j = 0; j < BS; j++) {
        int pos = base + j;
        if (pos < len) {
            size_t src = (size_t)(o0 + pos) * HD + h * D + d4 * 4;
            float4 kk = *(const float4*)(k + src);
            float4 vv = *(const float4*)(v + src);
            ks.x += kk.x; ks.y += kk.y; ks.z += kk.z; ks.w += kk.w;
            vs.x += vv.x; vs.y += vv.y; vs.z += vv.z; vs.w += vv.w;
        }
    }
    const float inv = 1.f / 32.f;
    ks.x *= inv; ks.y *= inv; ks.z *= inv; ks.w *= inv;
    vs.x *= inv; vs.y *= inv; vs.z *= inv; vs.w *= inv;
    *(float4*)(k_cmp + (size_t)idx * 4) = ks;
    *(float4*)(v_cmp + (size_t)idx * 4) = vs;
}

// ---------------------------------------------------------------------------
// K3: FUSED attention, 64-row Q-tile per workgroup (b, h, mtile).
// Phase C (per 32-row group g: qblk = 2*mtile+g): 3-plane split-bf16 MFMA QK
//   (fp32-equivalent selection scores), silu -> o_cmp PV, top-8 -> Ms.
// Phase S: DENSE kb = 0..2*mtile+1 loop (union of top-8 over 64 iid rows is
//   ~always all-causal-blocks — R6 counters), double-buffered K/V staging
//   from pre-converted bf16 kb16/vt_blk, per-row mask+causal, PV accumulate.
// MFMA layouts (m89/m120, R4/R6-verified): A[m=lane&15][k=quad*8+j];
//   C/D col=lane&15, row=quad*4+reg.
// ---------------------------------------------------------------------------
__global__ __launch_bounds__(256) void fused_attn(
    const float* __restrict__ q, const unsigned short* __restrict__ kb16,
    const unsigned short* __restrict__ vt_blk,
    const float* __restrict__ k_cmp, const float* __restrict__ v_cmp,
    const float* __restrict__ g, const int* __restrict__ offs,
    float* __restrict__ o_cmp_j, float* __restrict__ o_slc_j) {
    int x = blockIdx.x;                 // ((b*H + h)*16 + mtile)
    int mtile = x & 15;
    int h = (x >> 4) & 7;
    int b = x >> 7;
    int o0 = offs[b];
    int len = offs[b + 1] - o0;
    if (mtile * 64 >= len) return;      // uniform exit (len mult of 32; tiles of 64 divide all lens here)

    // LDS pool: phase C {Ks0,Ks1,Ks2,VTcmp} overlays phase S {Kbuf0,Kbuf1,VTbuf0,VTbuf1}
    __shared__ __align__(16) unsigned short pool[21504];
    __shared__ float Ss[32 * 33];
    __shared__ unsigned Ms[64];
    unsigned short* R0 = pool;           // 4352: Ks0  | Kbuf0 (32x136)
    unsigned short* R1 = pool + 4352;    // 4352: Ks1  | Kbuf1
    unsigned short* R2 = pool + 8704;    // 5120: Ks2  | VTbuf0 (128x40)
    unsigned short* R3 = pool + 13824;   // 5120: VTcmp| VTbuf1
    unsigned short* Ps = pool + 18944;   // 2560: P (64x40)

    int tid = threadIdx.x;
    int w = tid >> 6, lane = tid & 63;
    int r = lane & 15, quad = lane >> 4;
    int mt = w >> 1, jt = w & 1;        // phase C quadrant
    int stg_j = tid >> 3, stg_dc = tid & 7;

    // ---- phase C staging: k_cmp 3 planes + v_cmp^T (once per block) ----
    {
        const float* src = k_cmp + ((size_t)(b * NB + stg_j) * H + h) * D + stg_dc * 16;
        float xv[16];
        *(float4*)(xv + 0)  = *(const float4*)(src);
        *(float4*)(xv + 4)  = *(const float4*)(src + 4);
        *(float4*)(xv + 8)  = *(const float4*)(src + 8);
        *(float4*)(xv + 12) = *(const float4*)(src + 12);
        short8 a0, a1, a2, b0, b1, b2;
#pragma unroll
        for (int i = 0; i < 8; i++) {
            unsigned short e0, e1, e2;
            split3(xv[i], e0, e1, e2);
            a0[i] = (short)e0; a1[i] = (short)e1; a2[i] = (short)e2;
            split3(xv[8 + i], e0, e1, e2);
            b0[i] = (short)e0; b1[i] = (short)e1; b2[i] = (short)e2;
        }
        int ofs = stg_j * 136 + stg_dc * 16;
        *(short8*)(R0 + ofs) = a0; *(short8*)(R0 + ofs + 8) = b0;
        *(short8*)(R1 + ofs) = a1; *(short8*)(R1 + ofs + 8) = b1;
        *(short8*)(R2 + ofs) = a2; *(short8*)(R2 + ofs + 8) = b2;
        const float* vb = v_cmp + ((size_t)(b * NB + stg_j) * H + h) * D;
#pragma unroll
        for (int i = 0; i < 16; i++) {
            int d = stg_dc + 8 * i;
            R3[d * 40 + stg_j] = f2bf(vb[d]);
        }
    }
    __syncthreads();

    // ---- phase C groups (2 x 32 rows) ----
    for (int gq = 0; gq < 2; gq++) {
        int qblk = mtile * 2 + gq;
        short8 qf0[4], qf1[4], qf2[4];
        {
            const float* qrow = q + (size_t)(o0 + qblk * BS + mt * 16 + r) * HD + h * D;
#pragma unroll
            for (int s = 0; s < 4; s++) {
                const float* p0 = qrow + s * 32 + quad * 8;
                float xv[8];
                *(float4*)(xv) = *(const float4*)p0;
                *(float4*)(xv + 4) = *(const float4*)(p0 + 4);
                short8 f0, f1, f2;
#pragma unroll
                for (int i = 0; i < 8; i++) {
                    unsigned short e0, e1, e2;
                    split3(xv[i], e0, e1, e2);
                    f0[i] = (short)e0; f1[i] = (short)e1; f2[i] = (short)e2;
                }
                qf0[s] = f0; qf1[s] = f1; qf2[s] = f2;
            }
        }
        // QK: 6 product rounds, small terms first
        f32x4 sv = (f32x4){0.f, 0.f, 0.f, 0.f};
#pragma unroll
        for (int s = 0; s < 4; s++) {
            int ofs = (jt * 16 + r) * 136 + s * 32 + quad * 8;
            short8 k0 = *(const short8*)(R0 + ofs);
            short8 k1 = *(const short8*)(R1 + ofs);
            short8 k2 = *(const short8*)(R2 + ofs);
            sv = MFMA16(qf1[s], k1, sv);
            sv = MFMA16(qf0[s], k2, sv);
            sv = MFMA16(qf2[s], k0, sv);
            sv = MFMA16(qf0[s], k1, sv);
            sv = MFMA16(qf1[s], k0, sv);
            sv = MFMA16(qf0[s], k0, sv);
        }
        int colj = jt * 16 + r;
        bool causal = (colj <= qblk);
#pragma unroll
        for (int i = 0; i < 4; i++) {
            int mrow = mt * 16 + quad * 4 + i;      // 0..31 within group
            float sc = sv[i] * SCALE;
            Ss[mrow * 33 + colj] = causal ? sc : SENT;
            Ps[mrow * 40 + colj] = f2bf(causal ? silu(sc) : 0.f);
        }
        __syncthreads();

        // PV -> o_cmp
        f32x4 accC[2][2];
#pragma unroll
        for (int a = 0; a < 2; a++)
#pragma unroll
            for (int c = 0; c < 2; c++) accC[a][c] = (f32x4){0.f, 0.f, 0.f, 0.f};
        {
            short8 pf0 = *(const short8*)(Ps + r * 40 + quad * 8);
            short8 pf1 = *(const short8*)(Ps + (16 + r) * 40 + quad * 8);
            short8 vf0 = *(const short8*)(R3 + ((2 * w + 0) * 16 + r) * 40 + quad * 8);
            short8 vf1 = *(const short8*)(R3 + ((2 * w + 1) * 16 + r) * 40 + quad * 8);
            accC[0][0] = MFMA16(pf0, vf0, accC[0][0]);
            accC[0][1] = MFMA16(pf0, vf1, accC[0][1]);
            accC[1][0] = MFMA16(pf1, vf0, accC[1][0]);
            accC[1][1] = MFMA16(pf1, vf1, accC[1][1]);
        }
        // selection -> Ms
        if (qblk < S_SEL) {
            if (tid < BS) Ms[gq * BS + tid] = (1u << (qblk + 1)) - 1u;
        } else {
            int h2 = lane >> 5, l32 = lane & 31;
#pragma unroll
            for (int pass = 0; pass < 4; pass++) {
                int row = w * 8 + pass * 2 + h2;
                float val = Ss[row * 33 + l32];
                unsigned mask = 0;
                bool taken = false;
                for (int it = 0; it < S_SEL; it++) {
                    float vv = taken ? SENT : val;
                    int idx = l32;
#pragma unroll
                    for (int off = 16; off > 0; off >>= 1) {
                        float ov = __shfl_xor(vv, off);
                        int oi = __shfl_xor(idx, off);
                        if (ov > vv || (ov == vv && oi < idx)) { vv = ov; idx = oi; }
                    }
                    if (vv > -2.9e38f) {
                        mask |= (1u << idx);
                        if (idx == l32) taken = true;
                    }
                }
                if (l32 == 0) Ms[gq * BS + row] = mask;
            }
        }
        // epilogue o_cmp
#pragma unroll
        for (int mtl = 0; mtl < 2; mtl++) {
#pragma unroll
            for (int i = 0; i < 4; i++) {
                int mrow = mtl * 16 + quad * 4 + i;
                int gm = qblk * BS + mrow;
                float gc = g[(size_t)((b * NMAX + gm) * H + h) * 2];
                float* dst = o_cmp_j + (size_t)(o0 + gm) * HD + h * D;
                dst[(2 * w + 0) * 16 + r] = accC[mtl][0][i] * gc;
                dst[(2 * w + 1) * 16 + r] = accC[mtl][1][i] * gc;
            }
        }
        __syncthreads();                // Ss/Ps reuse next group / phase S
    }

    // ---- phase S: dense kb loop, double-buffered ----
    int qmax = mtile * 2 + 1;
    short8 qs[4];                       // plane-0 Q frags, wave rows 16w + r
    {
        const float* qrow = q + (size_t)(o0 + mtile * 64 + w * 16 + r) * HD + h * D;
#pragma unroll
        for (int s = 0; s < 4; s++) {
            const float* p0 = qrow + s * 32 + quad * 8;
            float xv[8];
            *(float4*)(xv) = *(const float4*)p0;
            *(float4*)(xv + 4) = *(const float4*)(p0 + 4);
            short8 f;
#pragma unroll
            for (int i = 0; i < 8; i++) f[i] = (short)f2bf(xv[i]);
            qs[s] = f;
        }
    }
    f32x4 acc[4][2];
#pragma unroll
    for (int a = 0; a < 4; a++)
#pragma unroll
        for (int c = 0; c < 2; c++) acc[a][c] = (f32x4){0.f, 0.f, 0.f, 0.f};

    size_t vtbase = (size_t)((b * H + h) * NB) * 4096;
    int vd = tid >> 1, vhf = tid & 1;

    // prestage kb = 0 into R0 (K) / R2 (VT)
    {
        const unsigned short* ks = kb16 + (size_t)(o0 + stg_j) * HD + h * D + stg_dc * 16;
        short8 k0 = *(const short8*)ks;
        short8 k1 = *(const short8*)(ks + 8);
        *(short8*)(R0 + stg_j * 136 + stg_dc * 16) = k0;
        *(short8*)(R0 + stg_j * 136 + stg_dc * 16 + 8) = k1;
        const unsigned short* vs = vt_blk + vtbase + tid * 16;
        short8 v0 = *(const short8*)vs;
        short8 v1 = *(const short8*)(vs + 8);
        *(short8*)(R2 + vd * 40 + vhf * 16) = v0;
        *(short8*)(R2 + vd * 40 + vhf * 16 + 8) = v1;
    }
    __syncthreads();

    unsigned short* Kb[2] = {R0, R1};
    unsigned short* Vb[2] = {R2, R3};
    int c = 0;
    for (int kb = 0; kb <= qmax; kb++) {
        short8 pk0, pk1, pv0, pv1;
        bool pf = (kb < qmax);
        if (pf) {                       // prefetch kb+1 into registers
            const unsigned short* ks = kb16 + (size_t)(o0 + (kb + 1) * BS + stg_j) * HD + h * D + stg_dc * 16;
            pk0 = *(const short8*)ks;
            pk1 = *(const short8*)(ks + 8);
            const unsigned short* vs = vt_blk + vtbase + (size_t)(kb + 1) * 4096 + tid * 16;
            pv0 = *(const short8*)vs;
            pv1 = *(const short8*)(vs + 8);
        }
        // QK: wave w -> rows [16w,16w+16), both j-frags
        unsigned short* K = Kb[c];
        f32x4 s0 = (f32x4){0.f, 0.f, 0.f, 0.f};
        f32x4 s1 = (f32x4){0.f, 0.f, 0.f, 0.f};
#pragma unroll
        for (int s = 0; s < 4; s++) {
            short8 kf0 = *(const short8*)(K + r * 136 + s * 32 + quad * 8);
            short8 kf1 = *(const short8*)(K + (16 + r) * 136 + s * 32 + quad * 8);
            s0 = MFMA16(qs[s], kf0, s0);
            s1 = MFMA16(qs[s], kf1, s1);
        }
#pragma unroll
        for (int jf = 0; jf < 2; jf++) {
            f32x4 svv = jf ? s1 : s0;
            int colj = jf * 16 + r;
            int kpos = kb * BS + colj;
#pragma unroll
            for (int i = 0; i < 4; i++) {
                int mrow = w * 16 + quad * 4 + i;
                int mpos = mtile * 64 + mrow;
                float p = (((Ms[mrow] >> kb) & 1u) && (kpos <= mpos))
                          ? silu(svv[i] * SCALE) : 0.f;
                Ps[mrow * 40 + colj] = f2bf(p);
            }
        }
        __syncthreads();
        // PV: wave w -> d-frags {2w, 2w+1}, all 4 m-frags
        unsigned short* V = Vb[c];
        {
            short8 vf0 = *(const short8*)(V + ((2 * w + 0) * 16 + r) * 40 + quad * 8);
            short8 vf1 = *(const short8*)(V + ((2 * w + 1) * 16 + r) * 40 + quad * 8);
#pragma unroll
            for (int mf = 0; mf < 4; mf++) {
                short8 pf8 = *(const short8*)(Ps + (mf * 16 + r) * 40 + quad * 8);
                acc[mf][0] = MFMA16(pf8, vf0, acc[mf][0]);
                acc[mf][1] = MFMA16(pf8, vf1, acc[mf][1]);
            }
        }
        if (pf) {                       // commit prefetch into the other buffer
            unsigned short* Kn = Kb[c ^ 1];
            unsigned short* Vn = Vb[c ^ 1];
            *(short8*)(Kn + stg_j * 136 + stg_dc * 16) = pk0;
            *(short8*)(Kn + stg_j * 136 + stg_dc * 16 + 8) = pk1;
            *(short8*)(Vn + vd * 40 + vhf * 16) = pv0;
            *(short8*)(Vn + vd * 40 + vhf * 16 + 8) = pv1;
        }
        __syncthreads();
        c ^= 1;
    }

    // epilogue o_slc
#pragma unroll
    for (int mf = 0; mf < 4; mf++) {
#pragma unroll
        for (int i = 0; i < 4; i++) {
            int mrow = mf * 16 + quad * 4 + i;
            int gm = mtile * 64 + mrow;
            float gs = g[(size_t)((b * NMAX + gm) * H + h) * 2 + 1];
            float* dst = o_slc_j + (size_t)(o0 + gm) * HD + h * D;
            dst[(2 * w + 0) * 16 + r] = acc[mf][0][i] * gs;
            dst[(2 * w + 1) * 16 + r] = acc[mf][1][i] * gs;
        }
    }
}

// ---------------------------------------------------------------------------
// K4: padded qp, kp (outputs 1,2) — runs AFTER fused (kp region may have been
// used as scratch for kb16/vt_blk when ws is small)
// ---------------------------------------------------------------------------
__global__ __launch_bounds__(256) void pad_qk_kernel(
    const float* __restrict__ q, const float* __restrict__ k,
    const int* __restrict__ offs,
    float* __restrict__ qp, float* __restrict__ kp) {
    int idx = blockIdx.x * 256 + threadIdx.x;       // float4 index over [B,n,H,D/4]
    int d4 = idx & 31;
    int h  = (idx >> 5) & 7;
    int m  = (idx >> 8) & (NMAX - 1);
    int b  = idx >> 18;
    int o0 = offs[b];
    int len = offs[b + 1] - o0;
    float4 qv = make_float4(0.f, 0.f, 0.f, 0.f);
    float4 kv = qv;
    if (m < len) {
        size_t src = (size_t)(o0 + m) * HD + h * D + d4 * 4;
        qv = *(const float4*)(q + src);
        kv = *(const float4*)(k + src);
    }
    *(float4*)(qp + (size_t)idx * 4) = qv;
    *(float4*)(kp + (size_t)idx * 4) = kv;
}

// ---------------------------------------------------------------------------
// K5: LayerNorm(1024) per stream, gate by u, sum -> out (oc may alias out)
// ---------------------------------------------------------------------------
__global__ __launch_bounds__(256) void ln_combine_kernel(
    const float* __restrict__ oc, const float* __restrict__ os,
    const float* __restrict__ u, float* __restrict__ out) {
    int t = blockIdx.x, tid = threadIdx.x;
    size_t base = (size_t)t * HD;
    float4 xc = *(const float4*)(oc + base + tid * 4);
    float4 xs = *(const float4*)(os + base + tid * 4);
    float4 uu = *(const float4*)(u + base + tid * 4);
    float s_c = xc.x + xc.y + xc.z + xc.w;
    float q_c = xc.x * xc.x + xc.y * xc.y + xc.z * xc.z + xc.w * xc.w;
    float s_s = xs.x + xs.y + xs.z + xs.w;
    float q_s = xs.x * xs.x + xs.y * xs.y + xs.z * xs.z + xs.w * xs.w;
#pragma unroll
    for (int off = 32; off > 0; off >>= 1) {
        s_c += __shfl_xor(s_c, off); q_c += __shfl_xor(q_c, off);
        s_s += __shfl_xor(s_s, off); q_s += __shfl_xor(q_s, off);
    }
    __shared__ float red[4][4];
    int w = tid >> 6, lane = tid & 63;
    if (lane == 0) {
        red[w][0] = s_c; red[w][1] = q_c; red[w][2] = s_s; red[w][3] = q_s;
    }
    __syncthreads();
    float tsc = red[0][0] + red[1][0] + red[2][0] + red[3][0];
    float tqc = red[0][1] + red[1][1] + red[2][1] + red[3][1];
    float tss = red[0][2] + red[1][2] + red[2][2] + red[3][2];
    float tqs = red[0][3] + red[1][3] + red[2][3] + red[3][3];
    const float inv = 1.f / 1024.f;
    float mc = tsc * inv, vc = tqc * inv - mc * mc;
    float ms = tss * inv, vs = tqs * inv - ms * ms;
    float rc = rsqrtf(vc + 1e-5f), rs = rsqrtf(vs + 1e-5f);
    float4 o;
    o.x = ((xc.x - mc) * rc + (xs.x - ms) * rs) * uu.x;
    o.y = ((xc.y - mc) * rc + (xs.y - ms) * rs) * uu.y;
    o.z = ((xc.z - mc) * rc + (xs.z - ms) * rs) * uu.z;
    o.w = ((xc.w - mc) * rc + (xs.w - ms) * rs) * uu.w;
    *(float4*)(out + base + tid * 4) = o;
}

// ---------------------------------------------------------------------------
extern "C" void kernel_launch(void* const* d_in, const int* in_sizes, int n_in,
                              void* d_out, int out_size, void* d_ws, size_t ws_size,
                              hipStream_t stream) {
    const float* q  = (const float*)d_in[0];
    const float* k  = (const float*)d_in[1];
    const float* v  = (const float*)d_in[2];
    const float* u  = (const float*)d_in[3];
    const float* Wg = (const float*)d_in[4];
    const float* bg = (const float*)d_in[5];
    const int* offs = (const int*)d_in[6];   // int32 (jnp default, x64 off)

    int B = in_sizes[6] - 1;
    int T = in_sizes[0] / HD;

    float* out = (float*)d_out;
    float* qp  = out + (size_t)T * HD;
    float* kp  = qp + (size_t)B * NMAX * HD;

    float* o_cmp_j = out;   // aliases final out (safe: see ln_combine)

    char* w = (char*)d_ws;
    float* k_cmp = (float*)w;            w += (size_t)B * NB * HD * 4;
    float* v_cmp = (float*)w;            w += (size_t)B * NB * HD * 4;
    float* g     = (float*)w;            w += (size_t)B * NMAX * H * 2 * 4;
    float* o_slc_j = (float*)w;          w += (size_t)T * HD * 4;

    // bf16 scratch: prefer ws tail; else use kp output region (rewritten after)
    size_t kb16_bytes = (size_t)T * HD * 2;
    size_t vt_bytes   = (size_t)B * H * NB * 128 * 32 * 2;
    size_t used = (size_t)(w - (char*)d_ws);
    char* scr = (used + kb16_bytes + vt_bytes <= ws_size) ? w : (char*)kp;
    unsigned short* kb16  = (unsigned short*)scr;
    unsigned short* vt_blk = (unsigned short*)(scr + kb16_bytes);

    int prepBlocks = B * H * NB;
    int cmpBlocks  = (B * NB * HD / 4) / 256;
    int fusBlocks  = B * H * 16;
    int padBlocks  = (B * NMAX * HD / 4) / 256;

    prep_kernel<<<prepBlocks, 256, 0, stream>>>(q, k, v, Wg, bg, offs, kb16, vt_blk, g);
    compress_kernel<<<cmpBlocks, 256, 0, stream>>>(k, v, offs, k_cmp, v_cmp);
    fused_attn<<<fusBlocks, 256, 0, stream>>>(q, kb16, vt_blk, k_cmp, v_cmp, g,
                                              offs, o_cmp_j, o_slc_j);
    pad_qk_kernel<<<padBlocks, 256, 0, stream>>>(q, k, offs, qp, kp);
    ln_combine_kernel<<<T, 256, 0, stream>>>(o_cmp_j, o_slc_j, u, out);
}